// Round 1
// baseline (1657.621 us; speedup 1.0000x reference)
//
#include <hip/hip_runtime.h>
#include <cstddef>

// ---------------------------------------------------------------------------
// GCN-VAE on MI355X. Pipeline:
//   CSR build (count/scan/fill) -> xw=x@W1 -> h=relu(A*xw+b1) -> hagg=A*h
//   -> mu,logvar = hagg@W +b -> z -> zagg=A*z -> recon=zagg@Wdx+b
//   -> fused gender/label/gumbel head.
// A = D^-1/2 (Adj + I) D^-1/2 applied via CSR-by-dst gather (no fp atomics).
// ---------------------------------------------------------------------------

__global__ void zero_int_kernel(int* __restrict__ p, int n) {
  int i = blockIdx.x * blockDim.x + threadIdx.x;
  if (i < n) p[i] = 0;
}

__global__ void count_kernel(const int* __restrict__ dst, int* __restrict__ deg, int e) {
  int i = blockIdx.x * blockDim.x + threadIdx.x;
  if (i < e) atomicAdd(&deg[dst[i]], 1);
}

// 3-phase exclusive scan over deg[n] -> rowptr[n] (+ rowptr[n]=total, cursor copy)
__global__ void scan_p1(const int* __restrict__ deg, int* __restrict__ part, int n) {
  __shared__ int s[256];
  int i = blockIdx.x * 256 + threadIdx.x;
  s[threadIdx.x] = (i < n) ? deg[i] : 0;
  __syncthreads();
  for (int off = 128; off > 0; off >>= 1) {
    if (threadIdx.x < off) s[threadIdx.x] += s[threadIdx.x + off];
    __syncthreads();
  }
  if (threadIdx.x == 0) part[blockIdx.x] = s[0];
}

__global__ void scan_p2(int* __restrict__ part, int nb, int* __restrict__ total_out) {
  __shared__ int s[256];
  int v = (threadIdx.x < nb) ? part[threadIdx.x] : 0;
  s[threadIdx.x] = v;
  __syncthreads();
  for (int off = 1; off < 256; off <<= 1) {
    int t = (threadIdx.x >= off) ? s[threadIdx.x - off] : 0;
    __syncthreads();
    s[threadIdx.x] += t;
    __syncthreads();
  }
  if (threadIdx.x < nb) part[threadIdx.x] = s[threadIdx.x] - v;  // exclusive
  if (threadIdx.x == nb - 1) *total_out = s[threadIdx.x];        // grand total
}

__global__ void scan_p3(const int* __restrict__ deg, const int* __restrict__ part,
                        int* __restrict__ rowptr, int* __restrict__ cursor, int n) {
  __shared__ int s[256];
  int i = blockIdx.x * 256 + threadIdx.x;
  int v = (i < n) ? deg[i] : 0;
  s[threadIdx.x] = v;
  __syncthreads();
  for (int off = 1; off < 256; off <<= 1) {
    int t = (threadIdx.x >= off) ? s[threadIdx.x - off] : 0;
    __syncthreads();
    s[threadIdx.x] += t;
    __syncthreads();
  }
  int excl = s[threadIdx.x] - v + part[blockIdx.x];
  if (i < n) { rowptr[i] = excl; cursor[i] = excl; }
}

__global__ void fill_kernel(const int* __restrict__ src, const int* __restrict__ dst,
                            int* __restrict__ cursor, int* __restrict__ csr, int e) {
  int i = blockIdx.x * blockDim.x + threadIdx.x;
  if (i < e) {
    int d = dst[i];
    int p = atomicAdd(&cursor[d], 1);
    csr[p] = src[i];
  }
}

__global__ void dinv_kernel(const int* __restrict__ deg, float* __restrict__ dinv, int n) {
  int i = blockIdx.x * blockDim.x + threadIdx.x;
  if (i < n) dinv[i] = 1.0f / sqrtf((float)deg[i] + 1.0f);  // +1 self-loop
}

// ---------------------------------------------------------------------------
// GEMM: C[n,M] = A[n,K] @ W[K,M] (+bias) (+relu). fp32 vector ALU.
// 256 threads: M/4 col-groups x (256/(M/4)) rows; W staged in LDS in K-tiles.
// ---------------------------------------------------------------------------
template <int K, int M, bool BIAS, bool RELU>
__global__ __launch_bounds__(256) void gemm_kernel(
    const float* __restrict__ A, const float* __restrict__ W,
    const float* __restrict__ bias, float* __restrict__ C, int n) {
  constexpr int KT = 32;
  constexpr int CG = M / 4;
  constexpr int ROWS = 256 / CG;
  __shared__ float sW[KT * M];
  __shared__ float sA[ROWS * K];
  const int tid = threadIdx.x;
  const int base = blockIdx.x * ROWS;
  for (int i = tid * 4; i < ROWS * K; i += 1024) {
    int r = i / K;
    int row = base + r;
    float4 v = {0.f, 0.f, 0.f, 0.f};
    if (row < n) v = *reinterpret_cast<const float4*>(&A[(size_t)row * K + (i - r * K)]);
    *reinterpret_cast<float4*>(&sA[i]) = v;
  }
  const int cg = tid % CG;
  const int r = tid / CG;
  float4 acc = {0.f, 0.f, 0.f, 0.f};
  for (int kt = 0; kt < K; kt += KT) {
    for (int i = tid * 4; i < KT * M; i += 1024)
      *reinterpret_cast<float4*>(&sW[i]) = *reinterpret_cast<const float4*>(&W[kt * M + i]);
    __syncthreads();
#pragma unroll
    for (int kk = 0; kk < KT; kk += 4) {
      float4 av = *reinterpret_cast<const float4*>(&sA[r * K + kt + kk]);
      float avs[4] = {av.x, av.y, av.z, av.w};
#pragma unroll
      for (int j = 0; j < 4; ++j) {
        float4 w = *reinterpret_cast<const float4*>(&sW[(kk + j) * M + cg * 4]);
        acc.x += avs[j] * w.x;
        acc.y += avs[j] * w.y;
        acc.z += avs[j] * w.z;
        acc.w += avs[j] * w.w;
      }
    }
    __syncthreads();
  }
  int row = base + r;
  if (row < n) {
    if (BIAS) {
      float4 b = *reinterpret_cast<const float4*>(&bias[cg * 4]);
      acc.x += b.x; acc.y += b.y; acc.z += b.z; acc.w += b.w;
    }
    if (RELU) {
      acc.x = fmaxf(acc.x, 0.f); acc.y = fmaxf(acc.y, 0.f);
      acc.z = fmaxf(acc.z, 0.f); acc.w = fmaxf(acc.w, 0.f);
    }
    *reinterpret_cast<float4*>(&C[(size_t)row * M + cg * 4]) = acc;
  }
}

// ---------------------------------------------------------------------------
// SpMM: Y[i] = dinv[i] * sum_{e: dst=i} X[src_e]*dinv[src_e] + dinv[i]^2 * X[i]
//        (+bias) (+relu).  One wave per node; indices batch-loaded + shfl-bcast.
// ---------------------------------------------------------------------------
template <int F, bool BIAS, bool RELU>
__global__ __launch_bounds__(256) void spmm_kernel(
    const float* __restrict__ X, float* __restrict__ Y,
    const int* __restrict__ rowptr, const int* __restrict__ csr,
    const float* __restrict__ dinv, const float* __restrict__ bias, int n) {
  int wid = (blockIdx.x * blockDim.x + threadIdx.x) >> 6;
  int lane = threadIdx.x & 63;
  if (wid >= n) return;
  int beg = rowptr[wid];
  int end = rowptr[wid + 1];
  constexpr int V = F / 64;
  float acc0 = 0.f, acc1 = 0.f;
  for (int base = beg; base < end; base += 64) {
    int m = end - base;
    if (m > 64) m = 64;
    int idx = 0;
    float dn = 0.f;
    if (lane < m) {
      idx = csr[base + lane];
      dn = dinv[idx];
    }
    for (int j = 0; j < m; ++j) {
      int s = __shfl(idx, j, 64);
      float d = __shfl(dn, j, 64);
      const float* row = X + (size_t)s * F;
      if (V == 2) {
        float2 v = *reinterpret_cast<const float2*>(row + lane * 2);
        acc0 += v.x * d;
        acc1 += v.y * d;
      } else {
        acc0 += row[lane] * d;
      }
    }
  }
  float di = dinv[wid];
  const float* srow = X + (size_t)wid * F;
  if (V == 2) {
    float2 sv = *reinterpret_cast<const float2*>(srow + lane * 2);
    float r0 = di * acc0 + di * di * sv.x;
    float r1 = di * acc1 + di * di * sv.y;
    if (BIAS) { r0 += bias[lane * 2]; r1 += bias[lane * 2 + 1]; }
    if (RELU) { r0 = fmaxf(r0, 0.f); r1 = fmaxf(r1, 0.f); }
    float2 o = {r0, r1};
    *reinterpret_cast<float2*>(Y + (size_t)wid * F + lane * 2) = o;
  } else {
    float r0 = di * acc0 + di * di * srow[lane];
    if (BIAS) r0 += bias[lane];
    if (RELU) r0 = fmaxf(r0, 0.f);
    Y[(size_t)wid * F + lane] = r0;
  }
}

__global__ void z_kernel(const float* __restrict__ eps, const float* __restrict__ lv,
                         const float* __restrict__ mu, float* __restrict__ z, int n) {
  int i = blockIdx.x * blockDim.x + threadIdx.x;
  if (i < n) z[i] = eps[i] * expf(0.5f * lv[i]) + mu[i];
}

// Fused: logits_gender = zagg@W_g + b_g ; logits_label = z@W_lc + b_lc ;
// gumbel-softmax hard (straight-through) on gender. One wave (64 lanes = LAT) per node.
__global__ __launch_bounds__(256) void gender_kernel(
    const float* __restrict__ zagg, const float* __restrict__ z,
    const float* __restrict__ Wg, const float* __restrict__ bg,
    const float* __restrict__ Wlc, const float* __restrict__ blc,
    const float* __restrict__ u,
    float* __restrict__ out_gender, float* __restrict__ out_label, int n) {
  int wid = (blockIdx.x * blockDim.x + threadIdx.x) >> 6;
  int lane = threadIdx.x & 63;
  if (wid >= n) return;
  float zg = zagg[(size_t)wid * 64 + lane];
  float zz = z[(size_t)wid * 64 + lane];
  float v0 = zg * Wg[lane * 2 + 0];
  float v1 = zg * Wg[lane * 2 + 1];
  float v2 = zz * Wlc[lane];
  for (int off = 32; off > 0; off >>= 1) {
    v0 += __shfl_xor(v0, off, 64);
    v1 += __shfl_xor(v1, off, 64);
    v2 += __shfl_xor(v2, off, 64);
  }
  if (lane == 0) {
    float lg0 = v0 + bg[0];
    float lg1 = v1 + bg[1];
    float ll = v2 + blc[0];
    float u0 = u[(size_t)wid * 2 + 0];
    float u1 = u[(size_t)wid * 2 + 1];
    float g0 = -logf(-logf(u0 + 1e-20f) + 1e-20f);
    float g1 = -logf(-logf(u1 + 1e-20f) + 1e-20f);
    float a0 = lg0 + g0, a1 = lg1 + g1;
    float mx = fmaxf(a0, a1);
    float e0 = expf(a0 - mx), e1 = expf(a1 - mx);
    float s = e0 + e1;
    float y0 = e0 / s, y1 = e1 / s;
    float h0 = (y1 > y0) ? 0.f : 1.f;  // argmax, first index wins ties
    float h1 = 1.f - h0;
    out_gender[(size_t)wid * 2 + 0] = (h0 - y0) + y0;  // straight-through forward
    out_gender[(size_t)wid * 2 + 1] = (h1 - y1) + y1;
    out_label[wid] = ll;
  }
}

extern "C" void kernel_launch(void* const* d_in, const int* in_sizes, int n_in,
                              void* d_out, int out_size, void* d_ws, size_t ws_size,
                              hipStream_t stream) {
  const float* x   = (const float*)d_in[0];
  const int*   ei  = (const int*)d_in[1];
  const float* eps = (const float*)d_in[2];
  const float* u   = (const float*)d_in[3];
  const float* W1  = (const float*)d_in[4];
  const float* b1  = (const float*)d_in[5];
  const float* Wmu = (const float*)d_in[6];
  const float* bmu = (const float*)d_in[7];
  const float* Wls = (const float*)d_in[8];
  const float* bls = (const float*)d_in[9];
  const float* Wdx = (const float*)d_in[10];
  const float* bdx = (const float*)d_in[11];
  const float* Wg  = (const float*)d_in[12];
  const float* bg  = (const float*)d_in[13];
  const float* Wlc = (const float*)d_in[14];
  const float* blc = (const float*)d_in[15];

  const int n = in_sizes[0] / 128;  // 50000
  const int e = in_sizes[1] / 2;    // 1600000
  const int* esrc = ei;
  const int* edst = ei + e;

  float* out = (float*)d_out;
  float* out_recon  = out;                            // n*128
  float* out_gender = out + (size_t)n * 128;          // n*2
  float* out_label  = out_gender + (size_t)n * 2;     // n
  float* out_mu     = out_label + n;                  // n*64
  float* out_lv     = out_mu + (size_t)n * 64;        // n*64
  float* out_z      = out_lv + (size_t)n * 64;        // n*64

  // Scratch: A lives in the recon output region (recon is written last, reads
  // only zagg). B + CSR structures live in d_ws (~33 MB).
  float* A = out_recon;                 // xw, then hagg
  float* B = (float*)d_ws;              // h (relu'd), then zagg
  float* dinv = B + (size_t)n * 128;
  int* deg    = (int*)(dinv + n);
  int* rowptr = deg + n;
  int* cursor = rowptr + (n + 1);
  int* part   = cursor + n;
  int* csr    = part + 256;

  const int NB = (n + 255) / 256;   // 196 (<=256 for scan_p2)
  const int EB = (e + 255) / 256;

  zero_int_kernel<<<NB, 256, 0, stream>>>(deg, n);
  count_kernel<<<EB, 256, 0, stream>>>(edst, deg, e);
  scan_p1<<<NB, 256, 0, stream>>>(deg, part, n);
  scan_p2<<<1, 256, 0, stream>>>(part, NB, &rowptr[n]);
  scan_p3<<<NB, 256, 0, stream>>>(deg, part, rowptr, cursor, n);
  fill_kernel<<<EB, 256, 0, stream>>>(esrc, edst, cursor, csr, e);
  dinv_kernel<<<NB, 256, 0, stream>>>(deg, dinv, n);

  // xw = x @ W1
  gemm_kernel<128, 128, false, false><<<(n + 7) / 8, 256, 0, stream>>>(x, W1, nullptr, A, n);
  // h = relu(A_hat * xw + b1)
  spmm_kernel<128, true, true><<<(n + 3) / 4, 256, 0, stream>>>(A, B, rowptr, csr, dinv, b1, n);
  // hagg = A_hat * h
  spmm_kernel<128, false, false><<<(n + 3) / 4, 256, 0, stream>>>(B, A, rowptr, csr, dinv, nullptr, n);
  // mu / logvar
  gemm_kernel<128, 64, true, false><<<(n + 15) / 16, 256, 0, stream>>>(A, Wmu, bmu, out_mu, n);
  gemm_kernel<128, 64, true, false><<<(n + 15) / 16, 256, 0, stream>>>(A, Wls, bls, out_lv, n);
  // z = eps * exp(0.5*logvar) + mu
  z_kernel<<<(n * 64 + 255) / 256, 256, 0, stream>>>(eps, out_lv, out_mu, out_z, n * 64);
  // zagg = A_hat * z
  spmm_kernel<64, false, false><<<(n + 3) / 4, 256, 0, stream>>>(out_z, B, rowptr, csr, dinv, nullptr, n);
  // recon = zagg @ W_dx + b_dx
  gemm_kernel<64, 128, true, false><<<(n + 7) / 8, 256, 0, stream>>>(B, Wdx, bdx, out_recon, n);
  // gender / label / gumbel head
  gender_kernel<<<(n + 3) / 4, 256, 0, stream>>>(B, out_z, Wg, bg, Wlc, blc, u, out_gender, out_label, n);
}

// Round 2
// 818.407 us; speedup vs baseline: 2.0254x; 2.0254x over previous
//
#include <hip/hip_runtime.h>
#include <cstddef>

// ---------------------------------------------------------------------------
// GCN-VAE on MI355X. Pipeline:
//   CSR build (count/scan/fill) -> xw=x@W1 -> h=relu(A*xw+b1) -> hagg=A*h
//   -> mu,logvar = hagg@W +b -> z -> zagg=A*z -> recon=zagg@Wdx+b
//   -> fused gender/label/gumbel head.
// A = D^-1/2 (Adj + I) D^-1/2 applied via CSR-by-dst gather (no fp atomics).
// R2: GEMM rewritten — R1 version spilled (VGPR=256, 850MB spill writes,
// 495us). New structure: W K-tiled in LDS, float4 acc[RPT] per thread,
// broadcast A loads, launch_bounds(256,4) caps VGPR at 128.
// ---------------------------------------------------------------------------

__global__ void zero_int_kernel(int* __restrict__ p, int n) {
  int i = blockIdx.x * blockDim.x + threadIdx.x;
  if (i < n) p[i] = 0;
}

__global__ void count_kernel(const int* __restrict__ dst, int* __restrict__ deg, int e) {
  int i = blockIdx.x * blockDim.x + threadIdx.x;
  if (i < e) atomicAdd(&deg[dst[i]], 1);
}

// 3-phase exclusive scan over deg[n] -> rowptr[n] (+ rowptr[n]=total, cursor copy)
__global__ void scan_p1(const int* __restrict__ deg, int* __restrict__ part, int n) {
  __shared__ int s[256];
  int i = blockIdx.x * 256 + threadIdx.x;
  s[threadIdx.x] = (i < n) ? deg[i] : 0;
  __syncthreads();
  for (int off = 128; off > 0; off >>= 1) {
    if (threadIdx.x < off) s[threadIdx.x] += s[threadIdx.x + off];
    __syncthreads();
  }
  if (threadIdx.x == 0) part[blockIdx.x] = s[0];
}

__global__ void scan_p2(int* __restrict__ part, int nb, int* __restrict__ total_out) {
  __shared__ int s[256];
  int v = (threadIdx.x < nb) ? part[threadIdx.x] : 0;
  s[threadIdx.x] = v;
  __syncthreads();
  for (int off = 1; off < 256; off <<= 1) {
    int t = (threadIdx.x >= off) ? s[threadIdx.x - off] : 0;
    __syncthreads();
    s[threadIdx.x] += t;
    __syncthreads();
  }
  if (threadIdx.x < nb) part[threadIdx.x] = s[threadIdx.x] - v;  // exclusive
  if (threadIdx.x == nb - 1) *total_out = s[threadIdx.x];        // grand total
}

__global__ void scan_p3(const int* __restrict__ deg, const int* __restrict__ part,
                        int* __restrict__ rowptr, int* __restrict__ cursor, int n) {
  __shared__ int s[256];
  int i = blockIdx.x * 256 + threadIdx.x;
  int v = (i < n) ? deg[i] : 0;
  s[threadIdx.x] = v;
  __syncthreads();
  for (int off = 1; off < 256; off <<= 1) {
    int t = (threadIdx.x >= off) ? s[threadIdx.x - off] : 0;
    __syncthreads();
    s[threadIdx.x] += t;
    __syncthreads();
  }
  int excl = s[threadIdx.x] - v + part[blockIdx.x];
  if (i < n) { rowptr[i] = excl; cursor[i] = excl; }
}

__global__ void fill_kernel(const int* __restrict__ src, const int* __restrict__ dst,
                            int* __restrict__ cursor, int* __restrict__ csr, int e) {
  int i = blockIdx.x * blockDim.x + threadIdx.x;
  if (i < e) {
    int d = dst[i];
    int p = atomicAdd(&cursor[d], 1);
    csr[p] = src[i];
  }
}

__global__ void dinv_kernel(const int* __restrict__ deg, float* __restrict__ dinv, int n) {
  int i = blockIdx.x * blockDim.x + threadIdx.x;
  if (i < n) dinv[i] = 1.0f / sqrtf((float)deg[i] + 1.0f);  // +1 self-loop
}

// ---------------------------------------------------------------------------
// GEMM: C[n,M] = A[n,K] @ W[K,M] (+bias) (+relu). fp32 vector ALU.
// Block 256 = (M/4) col-groups x RS row-slots; RPT rows per thread.
// W staged in LDS in KT-row tiles; A read via broadcast float4 global loads
// (all cg lanes of a row-slot hit the same address -> 1 transaction, L1).
// Per 4-k group: 4 ds_read_b128 + RPT global dwordx4 vs 16*RPT FMA -> VALU-bound.
// ---------------------------------------------------------------------------
template <int K, int M, int KT, int RPT, bool BIAS, bool RELU>
__global__ __launch_bounds__(256, 4) void gemm_kernel(
    const float* __restrict__ A, const float* __restrict__ W,
    const float* __restrict__ bias, float* __restrict__ C, int n) {
  constexpr int CG = M / 4;         // float4 col-groups
  constexpr int RS = 256 / CG;      // row-slots per block
  constexpr int RPB = RS * RPT;     // rows per block
  __shared__ float sW[KT * M];
  const int cg = threadIdx.x % CG;
  const int rs = threadIdx.x / CG;
  const int row0 = blockIdx.x * RPB + rs * RPT;

  const float* Arow[RPT];
#pragma unroll
  for (int rr = 0; rr < RPT; ++rr) {
    int row = row0 + rr;
    if (row > n - 1) row = n - 1;   // clamp: read valid memory, discard later
    Arow[rr] = A + (size_t)row * K;
  }

  float4 acc[RPT];
#pragma unroll
  for (int rr = 0; rr < RPT; ++rr) acc[rr] = float4{0.f, 0.f, 0.f, 0.f};

  for (int kt = 0; kt < K; kt += KT) {
    if (kt) __syncthreads();
    for (int i = threadIdx.x * 4; i < KT * M; i += 1024)
      *reinterpret_cast<float4*>(&sW[i]) =
          *reinterpret_cast<const float4*>(&W[kt * M + i]);
    __syncthreads();
#pragma unroll 4
    for (int k4 = 0; k4 < KT; k4 += 4) {
      float4 a[RPT];
#pragma unroll
      for (int rr = 0; rr < RPT; ++rr)
        a[rr] = *reinterpret_cast<const float4*>(Arow[rr] + kt + k4);
#pragma unroll
      for (int j = 0; j < 4; ++j) {
        float4 w = *reinterpret_cast<const float4*>(&sW[(k4 + j) * M + cg * 4]);
#pragma unroll
        for (int rr = 0; rr < RPT; ++rr) {
          float av = reinterpret_cast<const float*>(&a[rr])[j];
          acc[rr].x += av * w.x;
          acc[rr].y += av * w.y;
          acc[rr].z += av * w.z;
          acc[rr].w += av * w.w;
        }
      }
    }
  }

  float4 bv = float4{0.f, 0.f, 0.f, 0.f};
  if (BIAS) bv = *reinterpret_cast<const float4*>(&bias[cg * 4]);
#pragma unroll
  for (int rr = 0; rr < RPT; ++rr) {
    int row = row0 + rr;
    if (row < n) {
      float4 o = acc[rr];
      if (BIAS) { o.x += bv.x; o.y += bv.y; o.z += bv.z; o.w += bv.w; }
      if (RELU) {
        o.x = fmaxf(o.x, 0.f); o.y = fmaxf(o.y, 0.f);
        o.z = fmaxf(o.z, 0.f); o.w = fmaxf(o.w, 0.f);
      }
      *reinterpret_cast<float4*>(&C[(size_t)row * M + cg * 4]) = o;
    }
  }
}

// ---------------------------------------------------------------------------
// SpMM: Y[i] = dinv[i] * sum_{e: dst=i} X[src_e]*dinv[src_e] + dinv[i]^2 * X[i]
//        (+bias) (+relu).  One wave per node; indices batch-loaded + shfl-bcast.
// ---------------------------------------------------------------------------
template <int F, bool BIAS, bool RELU>
__global__ __launch_bounds__(256) void spmm_kernel(
    const float* __restrict__ X, float* __restrict__ Y,
    const int* __restrict__ rowptr, const int* __restrict__ csr,
    const float* __restrict__ dinv, const float* __restrict__ bias, int n) {
  int wid = (blockIdx.x * blockDim.x + threadIdx.x) >> 6;
  int lane = threadIdx.x & 63;
  if (wid >= n) return;
  int beg = rowptr[wid];
  int end = rowptr[wid + 1];
  constexpr int V = F / 64;
  float acc0 = 0.f, acc1 = 0.f;
  for (int base = beg; base < end; base += 64) {
    int m = end - base;
    if (m > 64) m = 64;
    int idx = 0;
    float dn = 0.f;
    if (lane < m) {
      idx = csr[base + lane];
      dn = dinv[idx];
    }
    for (int j = 0; j < m; ++j) {
      int s = __shfl(idx, j, 64);
      float d = __shfl(dn, j, 64);
      const float* row = X + (size_t)s * F;
      if (V == 2) {
        float2 v = *reinterpret_cast<const float2*>(row + lane * 2);
        acc0 += v.x * d;
        acc1 += v.y * d;
      } else {
        acc0 += row[lane] * d;
      }
    }
  }
  float di = dinv[wid];
  const float* srow = X + (size_t)wid * F;
  if (V == 2) {
    float2 sv = *reinterpret_cast<const float2*>(srow + lane * 2);
    float r0 = di * acc0 + di * di * sv.x;
    float r1 = di * acc1 + di * di * sv.y;
    if (BIAS) { r0 += bias[lane * 2]; r1 += bias[lane * 2 + 1]; }
    if (RELU) { r0 = fmaxf(r0, 0.f); r1 = fmaxf(r1, 0.f); }
    float2 o = {r0, r1};
    *reinterpret_cast<float2*>(Y + (size_t)wid * F + lane * 2) = o;
  } else {
    float r0 = di * acc0 + di * di * srow[lane];
    if (BIAS) r0 += bias[lane];
    if (RELU) r0 = fmaxf(r0, 0.f);
    Y[(size_t)wid * F + lane] = r0;
  }
}

__global__ void z_kernel(const float* __restrict__ eps, const float* __restrict__ lv,
                         const float* __restrict__ mu, float* __restrict__ z, int n) {
  int i = blockIdx.x * blockDim.x + threadIdx.x;
  if (i < n) z[i] = eps[i] * expf(0.5f * lv[i]) + mu[i];
}

// Fused: logits_gender = zagg@W_g + b_g ; logits_label = z@W_lc + b_lc ;
// gumbel-softmax hard (straight-through) on gender. One wave (64 lanes = LAT) per node.
__global__ __launch_bounds__(256) void gender_kernel(
    const float* __restrict__ zagg, const float* __restrict__ z,
    const float* __restrict__ Wg, const float* __restrict__ bg,
    const float* __restrict__ Wlc, const float* __restrict__ blc,
    const float* __restrict__ u,
    float* __restrict__ out_gender, float* __restrict__ out_label, int n) {
  int wid = (blockIdx.x * blockDim.x + threadIdx.x) >> 6;
  int lane = threadIdx.x & 63;
  if (wid >= n) return;
  float zg = zagg[(size_t)wid * 64 + lane];
  float zz = z[(size_t)wid * 64 + lane];
  float v0 = zg * Wg[lane * 2 + 0];
  float v1 = zg * Wg[lane * 2 + 1];
  float v2 = zz * Wlc[lane];
  for (int off = 32; off > 0; off >>= 1) {
    v0 += __shfl_xor(v0, off, 64);
    v1 += __shfl_xor(v1, off, 64);
    v2 += __shfl_xor(v2, off, 64);
  }
  if (lane == 0) {
    float lg0 = v0 + bg[0];
    float lg1 = v1 + bg[1];
    float ll = v2 + blc[0];
    float u0 = u[(size_t)wid * 2 + 0];
    float u1 = u[(size_t)wid * 2 + 1];
    float g0 = -logf(-logf(u0 + 1e-20f) + 1e-20f);
    float g1 = -logf(-logf(u1 + 1e-20f) + 1e-20f);
    float a0 = lg0 + g0, a1 = lg1 + g1;
    float mx = fmaxf(a0, a1);
    float e0 = expf(a0 - mx), e1 = expf(a1 - mx);
    float s = e0 + e1;
    float y0 = e0 / s, y1 = e1 / s;
    float h0 = (y1 > y0) ? 0.f : 1.f;  // argmax, first index wins ties
    float h1 = 1.f - h0;
    out_gender[(size_t)wid * 2 + 0] = (h0 - y0) + y0;  // straight-through forward
    out_gender[(size_t)wid * 2 + 1] = (h1 - y1) + y1;
    out_label[wid] = ll;
  }
}

extern "C" void kernel_launch(void* const* d_in, const int* in_sizes, int n_in,
                              void* d_out, int out_size, void* d_ws, size_t ws_size,
                              hipStream_t stream) {
  const float* x   = (const float*)d_in[0];
  const int*   ei  = (const int*)d_in[1];
  const float* eps = (const float*)d_in[2];
  const float* u   = (const float*)d_in[3];
  const float* W1  = (const float*)d_in[4];
  const float* b1  = (const float*)d_in[5];
  const float* Wmu = (const float*)d_in[6];
  const float* bmu = (const float*)d_in[7];
  const float* Wls = (const float*)d_in[8];
  const float* bls = (const float*)d_in[9];
  const float* Wdx = (const float*)d_in[10];
  const float* bdx = (const float*)d_in[11];
  const float* Wg  = (const float*)d_in[12];
  const float* bg  = (const float*)d_in[13];
  const float* Wlc = (const float*)d_in[14];
  const float* blc = (const float*)d_in[15];

  const int n = in_sizes[0] / 128;  // 50000
  const int e = in_sizes[1] / 2;    // 1600000
  const int* esrc = ei;
  const int* edst = ei + e;

  float* out = (float*)d_out;
  float* out_recon  = out;                            // n*128
  float* out_gender = out + (size_t)n * 128;          // n*2
  float* out_label  = out_gender + (size_t)n * 2;     // n
  float* out_mu     = out_label + n;                  // n*64
  float* out_lv     = out_mu + (size_t)n * 64;        // n*64
  float* out_z      = out_lv + (size_t)n * 64;        // n*64

  // Scratch: A lives in the recon output region (recon is written last, reads
  // only zagg). B + CSR structures live in d_ws (~33 MB).
  float* A = out_recon;                 // xw, then hagg
  float* B = (float*)d_ws;              // h (relu'd), then zagg
  float* dinv = B + (size_t)n * 128;
  int* deg    = (int*)(dinv + n);
  int* rowptr = deg + n;
  int* cursor = rowptr + (n + 1);
  int* part   = cursor + n;
  int* csr    = part + 256;

  const int NB = (n + 255) / 256;   // 196 (<=256 for scan_p2)
  const int EB = (e + 255) / 256;

  zero_int_kernel<<<NB, 256, 0, stream>>>(deg, n);
  count_kernel<<<EB, 256, 0, stream>>>(edst, deg, e);
  scan_p1<<<NB, 256, 0, stream>>>(deg, part, n);
  scan_p2<<<1, 256, 0, stream>>>(part, NB, &rowptr[n]);
  scan_p3<<<NB, 256, 0, stream>>>(deg, part, rowptr, cursor, n);
  fill_kernel<<<EB, 256, 0, stream>>>(esrc, edst, cursor, csr, e);
  dinv_kernel<<<NB, 256, 0, stream>>>(deg, dinv, n);

  // xw = x @ W1  (RPB = 8*4 = 32 rows/block)
  gemm_kernel<128, 128, 64, 4, false, false>
      <<<(n + 31) / 32, 256, 0, stream>>>(x, W1, nullptr, A, n);
  // h = relu(A_hat * xw + b1)
  spmm_kernel<128, true, true><<<(n + 3) / 4, 256, 0, stream>>>(A, B, rowptr, csr, dinv, b1, n);
  // hagg = A_hat * h
  spmm_kernel<128, false, false><<<(n + 3) / 4, 256, 0, stream>>>(B, A, rowptr, csr, dinv, nullptr, n);
  // mu / logvar  (RPB = 16*4 = 64 rows/block)
  gemm_kernel<128, 64, 64, 4, true, false>
      <<<(n + 63) / 64, 256, 0, stream>>>(A, Wmu, bmu, out_mu, n);
  gemm_kernel<128, 64, 64, 4, true, false>
      <<<(n + 63) / 64, 256, 0, stream>>>(A, Wls, bls, out_lv, n);
  // z = eps * exp(0.5*logvar) + mu
  z_kernel<<<(n * 64 + 255) / 256, 256, 0, stream>>>(eps, out_lv, out_mu, out_z, n * 64);
  // zagg = A_hat * z
  spmm_kernel<64, false, false><<<(n + 3) / 4, 256, 0, stream>>>(out_z, B, rowptr, csr, dinv, nullptr, n);
  // recon = zagg @ W_dx + b_dx  (K=64: single KT tile)
  gemm_kernel<64, 128, 64, 4, true, false>
      <<<(n + 31) / 32, 256, 0, stream>>>(B, Wdx, bdx, out_recon, n);
  // gender / label / gumbel head
  gender_kernel<<<(n + 3) / 4, 256, 0, stream>>>(B, out_z, Wg, bg, Wlc, blc, u, out_gender, out_label, n);
}

// Round 3
// 745.864 us; speedup vs baseline: 2.2224x; 1.0973x over previous
//
#include <hip/hip_runtime.h>
#include <cstddef>

// ---------------------------------------------------------------------------
// GCN-VAE on MI355X. Pipeline:
//   CSR build (count/scan/fill) -> xw=x@W1 -> h=relu(A*xw+b1) -> hagg=A*h
//   -> mu,logvar = hagg@W +b -> z -> zagg=A*z -> recon=zagg@Wdx+b
//   -> fused gender/label/gumbel head.
// A = D^-1/2 (Adj + I) D^-1/2 applied via CSR-by-dst gather (no fp atomics).
// R2: GEMM rewritten (R1 spilled: VGPR=256, 850MB spill writes, 495us/gemm).
// R3: fill cursor padded to 1 node / 64B line (R2: 16 cursors/line -> ~512
//     serialized RMWs per line, 138us). spmm j-loop unrolled x8 (R2: 1
//     outstanding gather/wave, LLC-latency-bound).
// ---------------------------------------------------------------------------

constexpr int CPAD = 16;  // cursor padding: one int per 64B line

__global__ void zero_int_kernel(int* __restrict__ p, int n) {
  int i = blockIdx.x * blockDim.x + threadIdx.x;
  if (i < n) p[i] = 0;
}

__global__ void count_kernel(const int* __restrict__ dst, int* __restrict__ deg, int e) {
  int i = blockIdx.x * blockDim.x + threadIdx.x;
  if (i < e) atomicAdd(&deg[dst[i]], 1);
}

// 3-phase exclusive scan over deg[n] -> rowptr[n] (+ rowptr[n]=total, cursor copy)
__global__ void scan_p1(const int* __restrict__ deg, int* __restrict__ part, int n) {
  __shared__ int s[256];
  int i = blockIdx.x * 256 + threadIdx.x;
  s[threadIdx.x] = (i < n) ? deg[i] : 0;
  __syncthreads();
  for (int off = 128; off > 0; off >>= 1) {
    if (threadIdx.x < off) s[threadIdx.x] += s[threadIdx.x + off];
    __syncthreads();
  }
  if (threadIdx.x == 0) part[blockIdx.x] = s[0];
}

__global__ void scan_p2(int* __restrict__ part, int nb, int* __restrict__ total_out) {
  __shared__ int s[256];
  int v = (threadIdx.x < nb) ? part[threadIdx.x] : 0;
  s[threadIdx.x] = v;
  __syncthreads();
  for (int off = 1; off < 256; off <<= 1) {
    int t = (threadIdx.x >= off) ? s[threadIdx.x - off] : 0;
    __syncthreads();
    s[threadIdx.x] += t;
    __syncthreads();
  }
  if (threadIdx.x < nb) part[threadIdx.x] = s[threadIdx.x] - v;  // exclusive
  if (threadIdx.x == nb - 1) *total_out = s[threadIdx.x];        // grand total
}

__global__ void scan_p3(const int* __restrict__ deg, const int* __restrict__ part,
                        int* __restrict__ rowptr, int* __restrict__ cursor, int n) {
  __shared__ int s[256];
  int i = blockIdx.x * 256 + threadIdx.x;
  int v = (i < n) ? deg[i] : 0;
  s[threadIdx.x] = v;
  __syncthreads();
  for (int off = 1; off < 256; off <<= 1) {
    int t = (threadIdx.x >= off) ? s[threadIdx.x - off] : 0;
    __syncthreads();
    s[threadIdx.x] += t;
    __syncthreads();
  }
  int excl = s[threadIdx.x] - v + part[blockIdx.x];
  if (i < n) { rowptr[i] = excl; cursor[i * CPAD] = excl; }
}

__global__ void fill_kernel(const int* __restrict__ src, const int* __restrict__ dst,
                            int* __restrict__ cursor, int* __restrict__ csr, int e) {
  int i = blockIdx.x * blockDim.x + threadIdx.x;
  if (i < e) {
    int d = dst[i];
    int p = atomicAdd(&cursor[d * CPAD], 1);
    csr[p] = src[i];
  }
}

__global__ void dinv_kernel(const int* __restrict__ deg, float* __restrict__ dinv, int n) {
  int i = blockIdx.x * blockDim.x + threadIdx.x;
  if (i < n) dinv[i] = 1.0f / sqrtf((float)deg[i] + 1.0f);  // +1 self-loop
}

// ---------------------------------------------------------------------------
// GEMM: C[n,M] = A[n,K] @ W[K,M] (+bias) (+relu). fp32 vector ALU.
// Block 256 = (M/4) col-groups x RS row-slots; RPT rows per thread.
// W staged in LDS in KT-row tiles; A read via broadcast float4 global loads.
// ---------------------------------------------------------------------------
template <int K, int M, int KT, int RPT, bool BIAS, bool RELU>
__global__ __launch_bounds__(256, 4) void gemm_kernel(
    const float* __restrict__ A, const float* __restrict__ W,
    const float* __restrict__ bias, float* __restrict__ C, int n) {
  constexpr int CG = M / 4;         // float4 col-groups
  constexpr int RS = 256 / CG;      // row-slots per block
  constexpr int RPB = RS * RPT;     // rows per block
  __shared__ float sW[KT * M];
  const int cg = threadIdx.x % CG;
  const int rs = threadIdx.x / CG;
  const int row0 = blockIdx.x * RPB + rs * RPT;

  const float* Arow[RPT];
#pragma unroll
  for (int rr = 0; rr < RPT; ++rr) {
    int row = row0 + rr;
    if (row > n - 1) row = n - 1;   // clamp: read valid memory, discard later
    Arow[rr] = A + (size_t)row * K;
  }

  float4 acc[RPT];
#pragma unroll
  for (int rr = 0; rr < RPT; ++rr) acc[rr] = float4{0.f, 0.f, 0.f, 0.f};

  for (int kt = 0; kt < K; kt += KT) {
    if (kt) __syncthreads();
    for (int i = threadIdx.x * 4; i < KT * M; i += 1024)
      *reinterpret_cast<float4*>(&sW[i]) =
          *reinterpret_cast<const float4*>(&W[kt * M + i]);
    __syncthreads();
#pragma unroll 4
    for (int k4 = 0; k4 < KT; k4 += 4) {
      float4 a[RPT];
#pragma unroll
      for (int rr = 0; rr < RPT; ++rr)
        a[rr] = *reinterpret_cast<const float4*>(Arow[rr] + kt + k4);
#pragma unroll
      for (int j = 0; j < 4; ++j) {
        float4 w = *reinterpret_cast<const float4*>(&sW[(k4 + j) * M + cg * 4]);
#pragma unroll
        for (int rr = 0; rr < RPT; ++rr) {
          float av = reinterpret_cast<const float*>(&a[rr])[j];
          acc[rr].x += av * w.x;
          acc[rr].y += av * w.y;
          acc[rr].z += av * w.z;
          acc[rr].w += av * w.w;
        }
      }
    }
  }

  float4 bv = float4{0.f, 0.f, 0.f, 0.f};
  if (BIAS) bv = *reinterpret_cast<const float4*>(&bias[cg * 4]);
#pragma unroll
  for (int rr = 0; rr < RPT; ++rr) {
    int row = row0 + rr;
    if (row < n) {
      float4 o = acc[rr];
      if (BIAS) { o.x += bv.x; o.y += bv.y; o.z += bv.z; o.w += bv.w; }
      if (RELU) {
        o.x = fmaxf(o.x, 0.f); o.y = fmaxf(o.y, 0.f);
        o.z = fmaxf(o.z, 0.f); o.w = fmaxf(o.w, 0.f);
      }
      *reinterpret_cast<float4*>(&C[(size_t)row * M + cg * 4]) = o;
    }
  }
}

// ---------------------------------------------------------------------------
// SpMM: Y[i] = dinv[i] * sum_{e: dst=i} X[src_e]*dinv[src_e] + dinv[i]^2 * X[i]
//        (+bias) (+relu).  One wave per node; indices batch-loaded + shfl-bcast.
// j-loop unrolled x8 with independent accumulators -> 8 gathers in flight.
// ---------------------------------------------------------------------------
template <int F, bool BIAS, bool RELU>
__global__ __launch_bounds__(256) void spmm_kernel(
    const float* __restrict__ X, float* __restrict__ Y,
    const int* __restrict__ rowptr, const int* __restrict__ csr,
    const float* __restrict__ dinv, const float* __restrict__ bias, int n) {
  int wid = (blockIdx.x * blockDim.x + threadIdx.x) >> 6;
  int lane = threadIdx.x & 63;
  if (wid >= n) return;
  int beg = rowptr[wid];
  int end = rowptr[wid + 1];
  constexpr int V = F / 64;
  constexpr int U = 8;
  float acc[U][V];
#pragma unroll
  for (int uu = 0; uu < U; ++uu)
#pragma unroll
    for (int vv = 0; vv < V; ++vv) acc[uu][vv] = 0.f;

  for (int base = beg; base < end; base += 64) {
    int m = end - base;
    if (m > 64) m = 64;
    int idx = 0;
    float dn = 0.f;
    if (lane < m) {
      idx = csr[base + lane];
      dn = dinv[idx];
    }
    int j = 0;
    for (; j + U <= m; j += U) {
      const float* rows[U];
      float d[U];
#pragma unroll
      for (int uu = 0; uu < U; ++uu) {
        int s = __shfl(idx, j + uu, 64);
        d[uu] = __shfl(dn, j + uu, 64);
        rows[uu] = X + (size_t)s * F;
      }
      if (V == 2) {
        float2 v[U];
#pragma unroll
        for (int uu = 0; uu < U; ++uu)
          v[uu] = *reinterpret_cast<const float2*>(rows[uu] + lane * 2);
#pragma unroll
        for (int uu = 0; uu < U; ++uu) {
          acc[uu][0] += v[uu].x * d[uu];
          acc[uu][V - 1] += v[uu].y * d[uu];
        }
      } else {
        float v[U];
#pragma unroll
        for (int uu = 0; uu < U; ++uu) v[uu] = rows[uu][lane];
#pragma unroll
        for (int uu = 0; uu < U; ++uu) acc[uu][0] += v[uu] * d[uu];
      }
    }
    for (; j < m; ++j) {
      int s = __shfl(idx, j, 64);
      float dd = __shfl(dn, j, 64);
      const float* row = X + (size_t)s * F;
      if (V == 2) {
        float2 v = *reinterpret_cast<const float2*>(row + lane * 2);
        acc[0][0] += v.x * dd;
        acc[0][V - 1] += v.y * dd;
      } else {
        acc[0][0] += row[lane] * dd;
      }
    }
  }

  float tot0 = 0.f, tot1 = 0.f;
#pragma unroll
  for (int uu = 0; uu < U; ++uu) {
    tot0 += acc[uu][0];
    if (V == 2) tot1 += acc[uu][V - 1];
  }

  float di = dinv[wid];
  const float* srow = X + (size_t)wid * F;
  if (V == 2) {
    float2 sv = *reinterpret_cast<const float2*>(srow + lane * 2);
    float r0 = di * tot0 + di * di * sv.x;
    float r1 = di * tot1 + di * di * sv.y;
    if (BIAS) { r0 += bias[lane * 2]; r1 += bias[lane * 2 + 1]; }
    if (RELU) { r0 = fmaxf(r0, 0.f); r1 = fmaxf(r1, 0.f); }
    float2 o = {r0, r1};
    *reinterpret_cast<float2*>(Y + (size_t)wid * F + lane * 2) = o;
  } else {
    float r0 = di * tot0 + di * di * srow[lane];
    if (BIAS) r0 += bias[lane];
    if (RELU) r0 = fmaxf(r0, 0.f);
    Y[(size_t)wid * F + lane] = r0;
  }
}

__global__ void z_kernel(const float* __restrict__ eps, const float* __restrict__ lv,
                         const float* __restrict__ mu, float* __restrict__ z, int n) {
  int i = blockIdx.x * blockDim.x + threadIdx.x;
  if (i < n) z[i] = eps[i] * expf(0.5f * lv[i]) + mu[i];
}

// Fused: logits_gender = zagg@W_g + b_g ; logits_label = z@W_lc + b_lc ;
// gumbel-softmax hard (straight-through) on gender. One wave (64 lanes = LAT) per node.
__global__ __launch_bounds__(256) void gender_kernel(
    const float* __restrict__ zagg, const float* __restrict__ z,
    const float* __restrict__ Wg, const float* __restrict__ bg,
    const float* __restrict__ Wlc, const float* __restrict__ blc,
    const float* __restrict__ u,
    float* __restrict__ out_gender, float* __restrict__ out_label, int n) {
  int wid = (blockIdx.x * blockDim.x + threadIdx.x) >> 6;
  int lane = threadIdx.x & 63;
  if (wid >= n) return;
  float zg = zagg[(size_t)wid * 64 + lane];
  float zz = z[(size_t)wid * 64 + lane];
  float v0 = zg * Wg[lane * 2 + 0];
  float v1 = zg * Wg[lane * 2 + 1];
  float v2 = zz * Wlc[lane];
  for (int off = 32; off > 0; off >>= 1) {
    v0 += __shfl_xor(v0, off, 64);
    v1 += __shfl_xor(v1, off, 64);
    v2 += __shfl_xor(v2, off, 64);
  }
  if (lane == 0) {
    float lg0 = v0 + bg[0];
    float lg1 = v1 + bg[1];
    float ll = v2 + blc[0];
    float u0 = u[(size_t)wid * 2 + 0];
    float u1 = u[(size_t)wid * 2 + 1];
    float g0 = -logf(-logf(u0 + 1e-20f) + 1e-20f);
    float g1 = -logf(-logf(u1 + 1e-20f) + 1e-20f);
    float a0 = lg0 + g0, a1 = lg1 + g1;
    float mx = fmaxf(a0, a1);
    float e0 = expf(a0 - mx), e1 = expf(a1 - mx);
    float s = e0 + e1;
    float y0 = e0 / s, y1 = e1 / s;
    float h0 = (y1 > y0) ? 0.f : 1.f;  // argmax, first index wins ties
    float h1 = 1.f - h0;
    out_gender[(size_t)wid * 2 + 0] = (h0 - y0) + y0;  // straight-through forward
    out_gender[(size_t)wid * 2 + 1] = (h1 - y1) + y1;
    out_label[wid] = ll;
  }
}

extern "C" void kernel_launch(void* const* d_in, const int* in_sizes, int n_in,
                              void* d_out, int out_size, void* d_ws, size_t ws_size,
                              hipStream_t stream) {
  const float* x   = (const float*)d_in[0];
  const int*   ei  = (const int*)d_in[1];
  const float* eps = (const float*)d_in[2];
  const float* u   = (const float*)d_in[3];
  const float* W1  = (const float*)d_in[4];
  const float* b1  = (const float*)d_in[5];
  const float* Wmu = (const float*)d_in[6];
  const float* bmu = (const float*)d_in[7];
  const float* Wls = (const float*)d_in[8];
  const float* bls = (const float*)d_in[9];
  const float* Wdx = (const float*)d_in[10];
  const float* bdx = (const float*)d_in[11];
  const float* Wg  = (const float*)d_in[12];
  const float* bg  = (const float*)d_in[13];
  const float* Wlc = (const float*)d_in[14];
  const float* blc = (const float*)d_in[15];

  const int n = in_sizes[0] / 128;  // 50000
  const int e = in_sizes[1] / 2;    // 1600000
  const int* esrc = ei;
  const int* edst = ei + e;

  float* out = (float*)d_out;
  float* out_recon  = out;                            // n*128
  float* out_gender = out + (size_t)n * 128;          // n*2
  float* out_label  = out_gender + (size_t)n * 2;     // n
  float* out_mu     = out_label + n;                  // n*64
  float* out_lv     = out_mu + (size_t)n * 64;        // n*64
  float* out_z      = out_lv + (size_t)n * 64;        // n*64

  // Scratch: A lives in the recon output region (recon is written last, reads
  // only zagg). Padded cursor (n*16 ints = 3.2MB) lives in the out_mu region,
  // which is free until the mu-GEMM (fill completes long before).
  float* A = out_recon;                 // xw, then hagg
  float* B = (float*)d_ws;              // h (relu'd), then zagg
  float* dinv = B + (size_t)n * 128;
  int* deg    = (int*)(dinv + n);
  int* rowptr = deg + n;
  int* part   = rowptr + (n + 1);
  int* csr    = part + 256;
  int* cursor = (int*)out_mu;           // n*CPAD ints (one per 64B line)

  const int NB = (n + 255) / 256;   // 196 (<=256 for scan_p2)
  const int EB = (e + 255) / 256;

  zero_int_kernel<<<NB, 256, 0, stream>>>(deg, n);
  count_kernel<<<EB, 256, 0, stream>>>(edst, deg, e);
  scan_p1<<<NB, 256, 0, stream>>>(deg, part, n);
  scan_p2<<<1, 256, 0, stream>>>(part, NB, &rowptr[n]);
  scan_p3<<<NB, 256, 0, stream>>>(deg, part, rowptr, cursor, n);
  fill_kernel<<<EB, 256, 0, stream>>>(esrc, edst, cursor, csr, e);
  dinv_kernel<<<NB, 256, 0, stream>>>(deg, dinv, n);

  // xw = x @ W1  (RPB = 8*4 = 32 rows/block)
  gemm_kernel<128, 128, 64, 4, false, false>
      <<<(n + 31) / 32, 256, 0, stream>>>(x, W1, nullptr, A, n);
  // h = relu(A_hat * xw + b1)
  spmm_kernel<128, true, true><<<(n + 3) / 4, 256, 0, stream>>>(A, B, rowptr, csr, dinv, b1, n);
  // hagg = A_hat * h
  spmm_kernel<128, false, false><<<(n + 3) / 4, 256, 0, stream>>>(B, A, rowptr, csr, dinv, nullptr, n);
  // mu / logvar  (RPB = 16*4 = 64 rows/block)  — overwrites cursor region (done with it)
  gemm_kernel<128, 64, 64, 4, true, false>
      <<<(n + 63) / 64, 256, 0, stream>>>(A, Wmu, bmu, out_mu, n);
  gemm_kernel<128, 64, 64, 4, true, false>
      <<<(n + 63) / 64, 256, 0, stream>>>(A, Wls, bls, out_lv, n);
  // z = eps * exp(0.5*logvar) + mu
  z_kernel<<<(n * 64 + 255) / 256, 256, 0, stream>>>(eps, out_lv, out_mu, out_z, n * 64);
  // zagg = A_hat * z
  spmm_kernel<64, false, false><<<(n + 3) / 4, 256, 0, stream>>>(out_z, B, rowptr, csr, dinv, nullptr, n);
  // recon = zagg @ W_dx + b_dx  (K=64: single KT tile)
  gemm_kernel<64, 128, 64, 4, true, false>
      <<<(n + 31) / 32, 256, 0, stream>>>(B, Wdx, bdx, out_recon, n);
  // gender / label / gumbel head
  gender_kernel<<<(n + 3) / 4, 256, 0, stream>>>(B, out_z, Wg, bg, Wlc, blc, u, out_gender, out_label, n);
}

// Round 4
// 606.870 us; speedup vs baseline: 2.7314x; 1.2290x over previous
//
#include <hip/hip_runtime.h>
#include <cstddef>

// ---------------------------------------------------------------------------
// GCN-VAE on MI355X. Pipeline:
//   CSR build (2-level LDS counting sort) -> xw=x@W1 -> h=relu(A*xw+b1)
//   -> hagg=A*h -> mu,logvar -> z -> zagg=A*z -> recon -> gender/label head.
// A = D^-1/2 (Adj + I) D^-1/2 applied via CSR-by-dst gather (no fp atomics).
// R2: GEMM rewritten (R1 spilled: VGPR=256, 850MB spill writes, 495us/gemm).
// R3: spmm j-loop unrolled x8 (1 outstanding gather -> 8). Cursor padding on
//     fill was ~neutral: fill was bound by csr 4B random scatter (101MB
//     line-writeback ping-pong across 8 XCDs), not atomic contention.
// R4: CSR build rewritten as 2-level counting sort: per-block LDS histograms
//     (no global atomics) -> scan -> block-private binned scatter -> per-
//     bucket LDS sort + coalesced csr writeout. count/fill kernels deleted.
// ---------------------------------------------------------------------------

constexpr int R = 200;        // nodes per bucket (n=50000 -> exactly 250 buckets)
constexpr int NBUCK = 250;    // dst buckets
constexpr int NBLK = 250;     // edge-chunk blocks for hist/scatter
constexpr int SLABCAP = 12288;  // csr slab LDS capacity (mean bucket = 6400 edges)

// Per-block histogram over dst buckets. gh[bucket*NBLK + block] (bucket-major
// so a flat exclusive scan yields per-(bucket,block) bases in csr order).
__global__ __launch_bounds__(256) void hist_kernel(
    const int* __restrict__ dst, int* __restrict__ gh, int e, int chunk) {
  __shared__ int h[NBUCK];
  for (int t = threadIdx.x; t < NBUCK; t += 256) h[t] = 0;
  __syncthreads();
  int beg = blockIdx.x * chunk;
  int fin = min(e, beg + chunk);
  for (int i = beg + threadIdx.x; i < fin; i += 256)
    atomicAdd(&h[dst[i] / R], 1);
  __syncthreads();
  for (int t = threadIdx.x; t < NBUCK; t += 256)
    gh[t * NBLK + blockIdx.x] = h[t];
}

// 3-phase exclusive scan (block=256). p1: block sums. p2: scan of sums
// (nb<=256). p3: in-place exclusive scan using block offsets.
__global__ void scan_p1(const int* __restrict__ in, int* __restrict__ part, int n) {
  __shared__ int s[256];
  int i = blockIdx.x * 256 + threadIdx.x;
  s[threadIdx.x] = (i < n) ? in[i] : 0;
  __syncthreads();
  for (int off = 128; off > 0; off >>= 1) {
    if (threadIdx.x < off) s[threadIdx.x] += s[threadIdx.x + off];
    __syncthreads();
  }
  if (threadIdx.x == 0) part[blockIdx.x] = s[0];
}

__global__ void scan_p2(int* __restrict__ part, int nb, int* __restrict__ total_out) {
  __shared__ int s[256];
  int v = (threadIdx.x < nb) ? part[threadIdx.x] : 0;
  s[threadIdx.x] = v;
  __syncthreads();
  for (int off = 1; off < 256; off <<= 1) {
    int t = (threadIdx.x >= off) ? s[threadIdx.x - off] : 0;
    __syncthreads();
    s[threadIdx.x] += t;
    __syncthreads();
  }
  if (threadIdx.x < nb) part[threadIdx.x] = s[threadIdx.x] - v;  // exclusive
  if (threadIdx.x == nb - 1) *total_out = s[threadIdx.x];        // grand total
}

// in-place: each element read into LDS before any write, so in==out is safe.
__global__ void scan_p3(int* io, const int* __restrict__ part, int n) {
  __shared__ int s[256];
  int i = blockIdx.x * 256 + threadIdx.x;
  int v = (i < n) ? io[i] : 0;
  s[threadIdx.x] = v;
  __syncthreads();
  for (int off = 1; off < 256; off <<= 1) {
    int t = (threadIdx.x >= off) ? s[threadIdx.x - off] : 0;
    __syncthreads();
    s[threadIdx.x] += t;
    __syncthreads();
  }
  int excl = s[threadIdx.x] - v + part[blockIdx.x];
  if (i < n) io[i] = excl;
}

// Scatter edges into bucket-binned order. Each (bucket,block) region is
// written by exactly one block -> each 64B line written back once (vs 16x
// ping-pong in the R3 atomic fill). Record = (dst%R)<<16 | src  (n<65536).
__global__ __launch_bounds__(256) void scatter_kernel(
    const int* __restrict__ src, const int* __restrict__ dst,
    const int* __restrict__ ghs, int* __restrict__ binned, int e, int chunk) {
  __shared__ int cur[NBUCK];
  for (int t = threadIdx.x; t < NBUCK; t += 256)
    cur[t] = ghs[t * NBLK + blockIdx.x];
  __syncthreads();
  int beg = blockIdx.x * chunk;
  int fin = min(e, beg + chunk);
  for (int i = beg + threadIdx.x; i < fin; i += 256) {
    int d = dst[i];
    int b = d / R;
    int p = atomicAdd(&cur[b], 1);
    binned[p] = ((d - b * R) << 16) | src[i];
  }
}

// One block per bucket: LDS degree count -> LDS scan -> rowptr/dinv writeout
// -> LDS scatter of srcs -> coalesced csr slab writeout.
__global__ __launch_bounds__(256) void final_kernel(
    const int* __restrict__ binned, const int* __restrict__ ghs,
    int* __restrict__ rowptr, int* __restrict__ csr,
    float* __restrict__ dinv, int n, int e) {
  __shared__ int sdeg[R];
  __shared__ int sscan[256];
  __shared__ int scur[R];
  __shared__ int slab[SLABCAP];
  const int b = blockIdx.x;
  const int tid = threadIdx.x;
  const int base = ghs[b * NBLK];
  const int end = (b < NBUCK - 1) ? ghs[(b + 1) * NBLK] : e;
  const int cnt = end - base;

  if (tid < R) sdeg[tid] = 0;
  __syncthreads();
  for (int k = base + tid; k < end; k += 256)
    atomicAdd(&sdeg[binned[k] >> 16], 1);
  __syncthreads();

  int dv = (tid < R) ? sdeg[tid] : 0;
  sscan[tid] = dv;
  __syncthreads();
  for (int off = 1; off < 256; off <<= 1) {
    int t = (tid >= off) ? sscan[tid - off] : 0;
    __syncthreads();
    sscan[tid] += t;
    __syncthreads();
  }
  int excl = sscan[tid] - dv;
  int node = b * R + tid;
  if (tid < R && node < n) {
    rowptr[node] = base + excl;
    dinv[node] = 1.0f / sqrtf((float)dv + 1.0f);  // +1 self-loop
    scur[tid] = excl;
  }
  __syncthreads();

  const bool fits = (cnt <= SLABCAP);
  for (int k = base + tid; k < end; k += 256) {
    int rec = binned[k];
    int p = atomicAdd(&scur[rec >> 16], 1);
    int s = rec & 0xFFFF;
    if (fits) slab[p] = s;
    else csr[base + p] = s;  // statistical-overflow fallback (uncoalesced)
  }
  __syncthreads();
  if (fits)
    for (int k = tid; k < cnt; k += 256) csr[base + k] = slab[k];
}

// ---------------------------------------------------------------------------
// GEMM: C[n,M] = A[n,K] @ W[K,M] (+bias) (+relu). fp32 vector ALU.
// ---------------------------------------------------------------------------
template <int K, int M, int KT, int RPT, bool BIAS, bool RELU>
__global__ __launch_bounds__(256, 4) void gemm_kernel(
    const float* __restrict__ A, const float* __restrict__ W,
    const float* __restrict__ bias, float* __restrict__ C, int n) {
  constexpr int CG = M / 4;         // float4 col-groups
  constexpr int RS = 256 / CG;      // row-slots per block
  constexpr int RPB = RS * RPT;     // rows per block
  __shared__ float sW[KT * M];
  const int cg = threadIdx.x % CG;
  const int rs = threadIdx.x / CG;
  const int row0 = blockIdx.x * RPB + rs * RPT;

  const float* Arow[RPT];
#pragma unroll
  for (int rr = 0; rr < RPT; ++rr) {
    int row = row0 + rr;
    if (row > n - 1) row = n - 1;   // clamp: read valid memory, discard later
    Arow[rr] = A + (size_t)row * K;
  }

  float4 acc[RPT];
#pragma unroll
  for (int rr = 0; rr < RPT; ++rr) acc[rr] = float4{0.f, 0.f, 0.f, 0.f};

  for (int kt = 0; kt < K; kt += KT) {
    if (kt) __syncthreads();
    for (int i = threadIdx.x * 4; i < KT * M; i += 1024)
      *reinterpret_cast<float4*>(&sW[i]) =
          *reinterpret_cast<const float4*>(&W[kt * M + i]);
    __syncthreads();
#pragma unroll 4
    for (int k4 = 0; k4 < KT; k4 += 4) {
      float4 a[RPT];
#pragma unroll
      for (int rr = 0; rr < RPT; ++rr)
        a[rr] = *reinterpret_cast<const float4*>(Arow[rr] + kt + k4);
#pragma unroll
      for (int j = 0; j < 4; ++j) {
        float4 w = *reinterpret_cast<const float4*>(&sW[(k4 + j) * M + cg * 4]);
#pragma unroll
        for (int rr = 0; rr < RPT; ++rr) {
          float av = reinterpret_cast<const float*>(&a[rr])[j];
          acc[rr].x += av * w.x;
          acc[rr].y += av * w.y;
          acc[rr].z += av * w.z;
          acc[rr].w += av * w.w;
        }
      }
    }
  }

  float4 bv = float4{0.f, 0.f, 0.f, 0.f};
  if (BIAS) bv = *reinterpret_cast<const float4*>(&bias[cg * 4]);
#pragma unroll
  for (int rr = 0; rr < RPT; ++rr) {
    int row = row0 + rr;
    if (row < n) {
      float4 o = acc[rr];
      if (BIAS) { o.x += bv.x; o.y += bv.y; o.z += bv.z; o.w += bv.w; }
      if (RELU) {
        o.x = fmaxf(o.x, 0.f); o.y = fmaxf(o.y, 0.f);
        o.z = fmaxf(o.z, 0.f); o.w = fmaxf(o.w, 0.f);
      }
      *reinterpret_cast<float4*>(&C[(size_t)row * M + cg * 4]) = o;
    }
  }
}

// ---------------------------------------------------------------------------
// SpMM: Y[i] = dinv[i] * sum_{e: dst=i} X[src_e]*dinv[src_e] + dinv[i]^2 * X[i]
//        (+bias) (+relu).  One wave per node; indices batch-loaded + shfl-bcast.
// j-loop unrolled x8 with independent accumulators -> 8 gathers in flight.
// ---------------------------------------------------------------------------
template <int F, bool BIAS, bool RELU>
__global__ __launch_bounds__(256) void spmm_kernel(
    const float* __restrict__ X, float* __restrict__ Y,
    const int* __restrict__ rowptr, const int* __restrict__ csr,
    const float* __restrict__ dinv, const float* __restrict__ bias, int n) {
  int wid = (blockIdx.x * blockDim.x + threadIdx.x) >> 6;
  int lane = threadIdx.x & 63;
  if (wid >= n) return;
  int beg = rowptr[wid];
  int end = rowptr[wid + 1];
  constexpr int V = F / 64;
  constexpr int U = 8;
  float acc[U][V];
#pragma unroll
  for (int uu = 0; uu < U; ++uu)
#pragma unroll
    for (int vv = 0; vv < V; ++vv) acc[uu][vv] = 0.f;

  for (int base = beg; base < end; base += 64) {
    int m = end - base;
    if (m > 64) m = 64;
    int idx = 0;
    float dn = 0.f;
    if (lane < m) {
      idx = csr[base + lane];
      dn = dinv[idx];
    }
    int j = 0;
    for (; j + U <= m; j += U) {
      const float* rows[U];
      float d[U];
#pragma unroll
      for (int uu = 0; uu < U; ++uu) {
        int s = __shfl(idx, j + uu, 64);
        d[uu] = __shfl(dn, j + uu, 64);
        rows[uu] = X + (size_t)s * F;
      }
      if (V == 2) {
        float2 v[U];
#pragma unroll
        for (int uu = 0; uu < U; ++uu)
          v[uu] = *reinterpret_cast<const float2*>(rows[uu] + lane * 2);
#pragma unroll
        for (int uu = 0; uu < U; ++uu) {
          acc[uu][0] += v[uu].x * d[uu];
          acc[uu][V - 1] += v[uu].y * d[uu];
        }
      } else {
        float v[U];
#pragma unroll
        for (int uu = 0; uu < U; ++uu) v[uu] = rows[uu][lane];
#pragma unroll
        for (int uu = 0; uu < U; ++uu) acc[uu][0] += v[uu] * d[uu];
      }
    }
    for (; j < m; ++j) {
      int s = __shfl(idx, j, 64);
      float dd = __shfl(dn, j, 64);
      const float* row = X + (size_t)s * F;
      if (V == 2) {
        float2 v = *reinterpret_cast<const float2*>(row + lane * 2);
        acc[0][0] += v.x * dd;
        acc[0][V - 1] += v.y * dd;
      } else {
        acc[0][0] += row[lane] * dd;
      }
    }
  }

  float tot0 = 0.f, tot1 = 0.f;
#pragma unroll
  for (int uu = 0; uu < U; ++uu) {
    tot0 += acc[uu][0];
    if (V == 2) tot1 += acc[uu][V - 1];
  }

  float di = dinv[wid];
  const float* srow = X + (size_t)wid * F;
  if (V == 2) {
    float2 sv = *reinterpret_cast<const float2*>(srow + lane * 2);
    float r0 = di * tot0 + di * di * sv.x;
    float r1 = di * tot1 + di * di * sv.y;
    if (BIAS) { r0 += bias[lane * 2]; r1 += bias[lane * 2 + 1]; }
    if (RELU) { r0 = fmaxf(r0, 0.f); r1 = fmaxf(r1, 0.f); }
    float2 o = {r0, r1};
    *reinterpret_cast<float2*>(Y + (size_t)wid * F + lane * 2) = o;
  } else {
    float r0 = di * tot0 + di * di * srow[lane];
    if (BIAS) r0 += bias[lane];
    if (RELU) r0 = fmaxf(r0, 0.f);
    Y[(size_t)wid * F + lane] = r0;
  }
}

__global__ void z_kernel(const float* __restrict__ eps, const float* __restrict__ lv,
                         const float* __restrict__ mu, float* __restrict__ z, int n) {
  int i = blockIdx.x * blockDim.x + threadIdx.x;
  if (i < n) z[i] = eps[i] * expf(0.5f * lv[i]) + mu[i];
}

// Fused: logits_gender = zagg@W_g + b_g ; logits_label = z@W_lc + b_lc ;
// gumbel-softmax hard (straight-through) on gender. One wave (64 lanes = LAT) per node.
__global__ __launch_bounds__(256) void gender_kernel(
    const float* __restrict__ zagg, const float* __restrict__ z,
    const float* __restrict__ Wg, const float* __restrict__ bg,
    const float* __restrict__ Wlc, const float* __restrict__ blc,
    const float* __restrict__ u,
    float* __restrict__ out_gender, float* __restrict__ out_label, int n) {
  int wid = (blockIdx.x * blockDim.x + threadIdx.x) >> 6;
  int lane = threadIdx.x & 63;
  if (wid >= n) return;
  float zg = zagg[(size_t)wid * 64 + lane];
  float zz = z[(size_t)wid * 64 + lane];
  float v0 = zg * Wg[lane * 2 + 0];
  float v1 = zg * Wg[lane * 2 + 1];
  float v2 = zz * Wlc[lane];
  for (int off = 32; off > 0; off >>= 1) {
    v0 += __shfl_xor(v0, off, 64);
    v1 += __shfl_xor(v1, off, 64);
    v2 += __shfl_xor(v2, off, 64);
  }
  if (lane == 0) {
    float lg0 = v0 + bg[0];
    float lg1 = v1 + bg[1];
    float ll = v2 + blc[0];
    float u0 = u[(size_t)wid * 2 + 0];
    float u1 = u[(size_t)wid * 2 + 1];
    float g0 = -logf(-logf(u0 + 1e-20f) + 1e-20f);
    float g1 = -logf(-logf(u1 + 1e-20f) + 1e-20f);
    float a0 = lg0 + g0, a1 = lg1 + g1;
    float mx = fmaxf(a0, a1);
    float e0 = expf(a0 - mx), e1 = expf(a1 - mx);
    float s = e0 + e1;
    float y0 = e0 / s, y1 = e1 / s;
    float h0 = (y1 > y0) ? 0.f : 1.f;  // argmax, first index wins ties
    float h1 = 1.f - h0;
    out_gender[(size_t)wid * 2 + 0] = (h0 - y0) + y0;  // straight-through forward
    out_gender[(size_t)wid * 2 + 1] = (h1 - y1) + y1;
    out_label[wid] = ll;
  }
}

extern "C" void kernel_launch(void* const* d_in, const int* in_sizes, int n_in,
                              void* d_out, int out_size, void* d_ws, size_t ws_size,
                              hipStream_t stream) {
  const float* x   = (const float*)d_in[0];
  const int*   ei  = (const int*)d_in[1];
  const float* eps = (const float*)d_in[2];
  const float* u   = (const float*)d_in[3];
  const float* W1  = (const float*)d_in[4];
  const float* b1  = (const float*)d_in[5];
  const float* Wmu = (const float*)d_in[6];
  const float* bmu = (const float*)d_in[7];
  const float* Wls = (const float*)d_in[8];
  const float* bls = (const float*)d_in[9];
  const float* Wdx = (const float*)d_in[10];
  const float* bdx = (const float*)d_in[11];
  const float* Wg  = (const float*)d_in[12];
  const float* bg  = (const float*)d_in[13];
  const float* Wlc = (const float*)d_in[14];
  const float* blc = (const float*)d_in[15];

  const int n = in_sizes[0] / 128;  // 50000
  const int e = in_sizes[1] / 2;    // 1600000
  const int* esrc = ei;
  const int* edst = ei + e;

  float* out = (float*)d_out;
  float* out_recon  = out;                            // n*128
  float* out_gender = out + (size_t)n * 128;          // n*2
  float* out_label  = out_gender + (size_t)n * 2;     // n
  float* out_mu     = out_label + n;                  // n*64
  float* out_lv     = out_mu + (size_t)n * 64;        // n*64
  float* out_z      = out_lv + (size_t)n * 64;        // n*64

  // Scratch layout. A lives in the recon output region (recon is written
  // last, reads only zagg). binned (6.4MB) borrows the out_lv region, which
  // is only written much later by the logvar GEMM.
  float* A = out_recon;                 // xw, then hagg
  float* B = (float*)d_ws;              // h (relu'd), then zagg
  float* dinv = B + (size_t)n * 128;
  int* rowptr = (int*)(dinv + n);       // n+1
  int* part   = rowptr + (n + 1);       // 256
  int* csr    = part + 256;             // e
  int* gh     = csr + e;                // NBUCK*NBLK (scanned in place)
  int* binned = (int*)out_lv;           // e packed records

  const int GH = NBUCK * NBLK;              // 62500
  const int GHB = (GH + 255) / 256;         // 245 (<=256 for scan_p2)
  const int chunk = (e + NBLK - 1) / NBLK;  // 6400

  // --- CSR build: 2-level counting sort ---
  hist_kernel<<<NBLK, 256, 0, stream>>>(edst, gh, e, chunk);
  scan_p1<<<GHB, 256, 0, stream>>>(gh, part, GH);
  scan_p2<<<1, 256, 0, stream>>>(part, GHB, &rowptr[n]);   // total == e
  scan_p3<<<GHB, 256, 0, stream>>>(gh, part, GH);
  scatter_kernel<<<NBLK, 256, 0, stream>>>(esrc, edst, gh, binned, e, chunk);
  final_kernel<<<NBUCK, 256, 0, stream>>>(binned, gh, rowptr, csr, dinv, n, e);

  // --- dense/sparse pipeline ---
  // xw = x @ W1  (RPB = 8*4 = 32 rows/block)
  gemm_kernel<128, 128, 64, 4, false, false>
      <<<(n + 31) / 32, 256, 0, stream>>>(x, W1, nullptr, A, n);
  // h = relu(A_hat * xw + b1)
  spmm_kernel<128, true, true><<<(n + 3) / 4, 256, 0, stream>>>(A, B, rowptr, csr, dinv, b1, n);
  // hagg = A_hat * h
  spmm_kernel<128, false, false><<<(n + 3) / 4, 256, 0, stream>>>(B, A, rowptr, csr, dinv, nullptr, n);
  // mu / logvar  (RPB = 16*4 = 64 rows/block); logvar GEMM overwrites binned (dead)
  gemm_kernel<128, 64, 64, 4, true, false>
      <<<(n + 63) / 64, 256, 0, stream>>>(A, Wmu, bmu, out_mu, n);
  gemm_kernel<128, 64, 64, 4, true, false>
      <<<(n + 63) / 64, 256, 0, stream>>>(A, Wls, bls, out_lv, n);
  // z = eps * exp(0.5*logvar) + mu
  z_kernel<<<(n * 64 + 255) / 256, 256, 0, stream>>>(eps, out_lv, out_mu, out_z, n * 64);
  // zagg = A_hat * z
  spmm_kernel<64, false, false><<<(n + 3) / 4, 256, 0, stream>>>(out_z, B, rowptr, csr, dinv, nullptr, n);
  // recon = zagg @ W_dx + b_dx  (K=64: single KT tile)
  gemm_kernel<64, 128, 64, 4, true, false>
      <<<(n + 31) / 32, 256, 0, stream>>>(B, Wdx, bdx, out_recon, n);
  // gender / label / gumbel head
  gender_kernel<<<(n + 3) / 4, 256, 0, stream>>>(B, out_z, Wg, bg, Wlc, blc, u, out_gender, out_label, n);
}

// Round 5
// 487.542 us; speedup vs baseline: 3.4000x; 1.2448x over previous
//
#include <hip/hip_runtime.h>
#include <hip/hip_fp16.h>
#include <cstddef>

// ---------------------------------------------------------------------------
// GCN-VAE on MI355X.
//   CSR build (2-level LDS counting sort) -> xw=x@W1 (staged fp16*dinv)
//   -> h (spmm, staged fp16*dinv) -> hagg (spmm, fp32) -> mu,logvar -> z
//   (out fp32 + staged fp16*dinv) -> zagg (spmm) -> recon
//   gender: zg = z@W_g (fp32, commuted) -> gagg = A*zg (2-feat fp32) -> head.
// R2: GEMM rewritten (R1 spilled: 850MB spill writes).
// R3: spmm x8 unroll; learned fill was bound by csr line ping-pong not atomics.
// R4: CSR build as counting sort; spmm now top: FETCH 359MB/dispatch (57% L2
//     hit on E*512B gather), 3.8TB/s, VALU 18% -> byte-volume bound.
// R5: fp16 dinv-prescaled staging halves gather bytes; dinv gather deleted.
//     Gender conv commuted to Â(z@Wg)=(Âz)@Wg BEFORE aggregation so the
//     one-hot argmax path stays fp32-exact (flip = absmax 1.0 cliff).
// ---------------------------------------------------------------------------

constexpr int R = 200;        // nodes per bucket (n=50000 -> exactly 250 buckets)
constexpr int NBUCK = 250;    // dst buckets
constexpr int NBLK = 250;     // edge-chunk blocks for hist/scatter
constexpr int SLABCAP = 12288;  // csr slab LDS capacity (mean bucket = 6400)

__global__ __launch_bounds__(256) void hist_kernel(
    const int* __restrict__ dst, int* __restrict__ gh, int e, int chunk) {
  __shared__ int h[NBUCK];
  for (int t = threadIdx.x; t < NBUCK; t += 256) h[t] = 0;
  __syncthreads();
  int beg = blockIdx.x * chunk;
  int fin = min(e, beg + chunk);
  for (int i = beg + threadIdx.x; i < fin; i += 256)
    atomicAdd(&h[dst[i] / R], 1);
  __syncthreads();
  for (int t = threadIdx.x; t < NBUCK; t += 256)
    gh[t * NBLK + blockIdx.x] = h[t];
}

__global__ void scan_p1(const int* __restrict__ in, int* __restrict__ part, int n) {
  __shared__ int s[256];
  int i = blockIdx.x * 256 + threadIdx.x;
  s[threadIdx.x] = (i < n) ? in[i] : 0;
  __syncthreads();
  for (int off = 128; off > 0; off >>= 1) {
    if (threadIdx.x < off) s[threadIdx.x] += s[threadIdx.x + off];
    __syncthreads();
  }
  if (threadIdx.x == 0) part[blockIdx.x] = s[0];
}

__global__ void scan_p2(int* __restrict__ part, int nb, int* __restrict__ total_out) {
  __shared__ int s[256];
  int v = (threadIdx.x < nb) ? part[threadIdx.x] : 0;
  s[threadIdx.x] = v;
  __syncthreads();
  for (int off = 1; off < 256; off <<= 1) {
    int t = (threadIdx.x >= off) ? s[threadIdx.x - off] : 0;
    __syncthreads();
    s[threadIdx.x] += t;
    __syncthreads();
  }
  if (threadIdx.x < nb) part[threadIdx.x] = s[threadIdx.x] - v;  // exclusive
  if (threadIdx.x == nb - 1) *total_out = s[threadIdx.x];        // grand total
}

__global__ void scan_p3(int* io, const int* __restrict__ part, int n) {
  __shared__ int s[256];
  int i = blockIdx.x * 256 + threadIdx.x;
  int v = (i < n) ? io[i] : 0;
  s[threadIdx.x] = v;
  __syncthreads();
  for (int off = 1; off < 256; off <<= 1) {
    int t = (threadIdx.x >= off) ? s[threadIdx.x - off] : 0;
    __syncthreads();
    s[threadIdx.x] += t;
    __syncthreads();
  }
  int excl = s[threadIdx.x] - v + part[blockIdx.x];
  if (i < n) io[i] = excl;
}

// Record = (dst%R)<<16 | src  (n<65536). Block-private regions: one
// writeback per 64B line.
__global__ __launch_bounds__(256) void scatter_kernel(
    const int* __restrict__ src, const int* __restrict__ dst,
    const int* __restrict__ ghs, int* __restrict__ binned, int e, int chunk) {
  __shared__ int cur[NBUCK];
  for (int t = threadIdx.x; t < NBUCK; t += 256)
    cur[t] = ghs[t * NBLK + blockIdx.x];
  __syncthreads();
  int beg = blockIdx.x * chunk;
  int fin = min(e, beg + chunk);
  for (int i = beg + threadIdx.x; i < fin; i += 256) {
    int d = dst[i];
    int b = d / R;
    int p = atomicAdd(&cur[b], 1);
    binned[p] = ((d - b * R) << 16) | src[i];
  }
}

__global__ __launch_bounds__(256) void final_kernel(
    const int* __restrict__ binned, const int* __restrict__ ghs,
    int* __restrict__ rowptr, int* __restrict__ csr,
    float* __restrict__ dinv, int n, int e) {
  __shared__ int sdeg[R];
  __shared__ int sscan[256];
  __shared__ int scur[R];
  __shared__ int slab[SLABCAP];
  const int b = blockIdx.x;
  const int tid = threadIdx.x;
  const int base = ghs[b * NBLK];
  const int end = (b < NBUCK - 1) ? ghs[(b + 1) * NBLK] : e;
  const int cnt = end - base;

  if (tid < R) sdeg[tid] = 0;
  __syncthreads();
  for (int k = base + tid; k < end; k += 256)
    atomicAdd(&sdeg[binned[k] >> 16], 1);
  __syncthreads();

  int dv = (tid < R) ? sdeg[tid] : 0;
  sscan[tid] = dv;
  __syncthreads();
  for (int off = 1; off < 256; off <<= 1) {
    int t = (tid >= off) ? sscan[tid - off] : 0;
    __syncthreads();
    sscan[tid] += t;
    __syncthreads();
  }
  int excl = sscan[tid] - dv;
  int node = b * R + tid;
  if (tid < R && node < n) {
    rowptr[node] = base + excl;
    dinv[node] = 1.0f / sqrtf((float)dv + 1.0f);  // +1 self-loop
    scur[tid] = excl;
  }
  __syncthreads();

  const bool fits = (cnt <= SLABCAP);
  for (int k = base + tid; k < end; k += 256) {
    int rec = binned[k];
    int p = atomicAdd(&scur[rec >> 16], 1);
    int s = rec & 0xFFFF;
    if (fits) slab[p] = s;
    else csr[base + p] = s;
  }
  __syncthreads();
  if (fits)
    for (int k = tid; k < cnt; k += 256) csr[base + k] = slab[k];
}

// ---------------------------------------------------------------------------
// GEMM: C[n,M] = A[n,K] @ W[K,M] (+bias)(+relu). HALF_OUT: writes ONLY the
// fp16 dinv-prescaled staging buffer Ch[row] = fp16(dinv[row]*val).
// ---------------------------------------------------------------------------
template <int K, int M, int KT, int RPT, bool BIAS, bool RELU, bool HALF_OUT>
__global__ __launch_bounds__(256, 4) void gemm_kernel(
    const float* __restrict__ A, const float* __restrict__ W,
    const float* __restrict__ bias, float* __restrict__ C,
    __half* __restrict__ Ch, const float* __restrict__ dinv, int n) {
  constexpr int CG = M / 4;
  constexpr int RS = 256 / CG;
  constexpr int RPB = RS * RPT;
  __shared__ float sW[KT * M];
  const int cg = threadIdx.x % CG;
  const int rs = threadIdx.x / CG;
  const int row0 = blockIdx.x * RPB + rs * RPT;

  const float* Arow[RPT];
#pragma unroll
  for (int rr = 0; rr < RPT; ++rr) {
    int row = row0 + rr;
    if (row > n - 1) row = n - 1;
    Arow[rr] = A + (size_t)row * K;
  }

  float4 acc[RPT];
#pragma unroll
  for (int rr = 0; rr < RPT; ++rr) acc[rr] = float4{0.f, 0.f, 0.f, 0.f};

  for (int kt = 0; kt < K; kt += KT) {
    if (kt) __syncthreads();
    for (int i = threadIdx.x * 4; i < KT * M; i += 1024)
      *reinterpret_cast<float4*>(&sW[i]) =
          *reinterpret_cast<const float4*>(&W[kt * M + i]);
    __syncthreads();
#pragma unroll 4
    for (int k4 = 0; k4 < KT; k4 += 4) {
      float4 a[RPT];
#pragma unroll
      for (int rr = 0; rr < RPT; ++rr)
        a[rr] = *reinterpret_cast<const float4*>(Arow[rr] + kt + k4);
#pragma unroll
      for (int j = 0; j < 4; ++j) {
        float4 w = *reinterpret_cast<const float4*>(&sW[(k4 + j) * M + cg * 4]);
#pragma unroll
        for (int rr = 0; rr < RPT; ++rr) {
          float av = reinterpret_cast<const float*>(&a[rr])[j];
          acc[rr].x += av * w.x;
          acc[rr].y += av * w.y;
          acc[rr].z += av * w.z;
          acc[rr].w += av * w.w;
        }
      }
    }
  }

  float4 bv = float4{0.f, 0.f, 0.f, 0.f};
  if (BIAS) bv = *reinterpret_cast<const float4*>(&bias[cg * 4]);
#pragma unroll
  for (int rr = 0; rr < RPT; ++rr) {
    int row = row0 + rr;
    if (row < n) {
      float4 o = acc[rr];
      if (BIAS) { o.x += bv.x; o.y += bv.y; o.z += bv.z; o.w += bv.w; }
      if (RELU) {
        o.x = fmaxf(o.x, 0.f); o.y = fmaxf(o.y, 0.f);
        o.z = fmaxf(o.z, 0.f); o.w = fmaxf(o.w, 0.f);
      }
      if (HALF_OUT) {
        float di = dinv[row];
        __half2* dst = reinterpret_cast<__half2*>(Ch + (size_t)row * M + cg * 4);
        dst[0] = __floats2half2_rn(di * o.x, di * o.y);
        dst[1] = __floats2half2_rn(di * o.z, di * o.w);
      } else {
        *reinterpret_cast<float4*>(&C[(size_t)row * M + cg * 4]) = o;
      }
    }
  }
}

// ---------------------------------------------------------------------------
// SpMM on fp16 dinv-prescaled input Xs (Xs[i] = dinv[i]*X[i]):
//   Y[i] = dinv[i] * (sum_{e: dst=i} Xs[src_e] + Xs[i]) (+bias)(+relu)
// One wave per node; indices batch-loaded + shfl-bcast; x8 unroll.
// HALF_OUT: writes fp16(dinv[i]*Y[i]) staging for the next layer.
// ---------------------------------------------------------------------------
template <int F, bool BIAS, bool RELU, bool HALF_OUT>
__global__ __launch_bounds__(256) void spmm_kernel(
    const __half* __restrict__ Xs, void* __restrict__ Yout,
    const int* __restrict__ rowptr, const int* __restrict__ csr,
    const float* __restrict__ dinv, const float* __restrict__ bias, int n) {
  int wid = (blockIdx.x * blockDim.x + threadIdx.x) >> 6;
  int lane = threadIdx.x & 63;
  if (wid >= n) return;
  int beg = rowptr[wid];
  int end = rowptr[wid + 1];
  constexpr int V = F / 64;
  constexpr int U = 8;
  float acc0[U], acc1[U];
#pragma unroll
  for (int uu = 0; uu < U; ++uu) { acc0[uu] = 0.f; acc1[uu] = 0.f; }

  for (int base = beg; base < end; base += 64) {
    int m = end - base;
    if (m > 64) m = 64;
    int idx = (lane < m) ? csr[base + lane] : 0;
    int j = 0;
    for (; j + U <= m; j += U) {
      const __half* rows[U];
#pragma unroll
      for (int uu = 0; uu < U; ++uu)
        rows[uu] = Xs + (size_t)__shfl(idx, j + uu, 64) * F;
      if (V == 2) {
        __half2 v[U];
#pragma unroll
        for (int uu = 0; uu < U; ++uu)
          v[uu] = reinterpret_cast<const __half2*>(rows[uu])[lane];
#pragma unroll
        for (int uu = 0; uu < U; ++uu) {
          float2 f = __half22float2(v[uu]);
          acc0[uu] += f.x;
          acc1[uu] += f.y;
        }
      } else {
        __half v[U];
#pragma unroll
        for (int uu = 0; uu < U; ++uu) v[uu] = rows[uu][lane];
#pragma unroll
        for (int uu = 0; uu < U; ++uu) acc0[uu] += __half2float(v[uu]);
      }
    }
    for (; j < m; ++j) {
      const __half* row = Xs + (size_t)__shfl(idx, j, 64) * F;
      if (V == 2) {
        float2 f = __half22float2(reinterpret_cast<const __half2*>(row)[lane]);
        acc0[0] += f.x;
        acc1[0] += f.y;
      } else {
        acc0[0] += __half2float(row[lane]);
      }
    }
  }

  float t0 = 0.f, t1 = 0.f;
#pragma unroll
  for (int uu = 0; uu < U; ++uu) { t0 += acc0[uu]; t1 += acc1[uu]; }

  // self-loop term: + Xs[wid] (= dinv[wid]*X[wid])
  const __half* srow = Xs + (size_t)wid * F;
  if (V == 2) {
    float2 sf = __half22float2(reinterpret_cast<const __half2*>(srow)[lane]);
    t0 += sf.x;
    t1 += sf.y;
  } else {
    t0 += __half2float(srow[lane]);
  }

  float di = dinv[wid];
  float r0 = di * t0;
  float r1 = di * t1;
  if (BIAS) {
    if (V == 2) { r0 += bias[lane * 2]; r1 += bias[lane * 2 + 1]; }
    else r0 += bias[lane];
  }
  if (RELU) { r0 = fmaxf(r0, 0.f); r1 = fmaxf(r1, 0.f); }

  if (HALF_OUT) {
    __half* Yh = (__half*)Yout;
    if (V == 2)
      reinterpret_cast<__half2*>(Yh + (size_t)wid * F)[lane] =
          __floats2half2_rn(di * r0, di * r1);
    else
      Yh[(size_t)wid * F + lane] = __float2half(di * r0);
  } else {
    float* Yf = (float*)Yout;
    if (V == 2) {
      float2 o = {r0, r1};
      reinterpret_cast<float2*>(Yf + (size_t)wid * F)[lane] = o;
    } else {
      Yf[(size_t)wid * F + lane] = r0;
    }
  }
}

__global__ void z_kernel(const float* __restrict__ eps, const float* __restrict__ lv,
                         const float* __restrict__ mu, float* __restrict__ z,
                         __half* __restrict__ zh, const float* __restrict__ dinv,
                         int n64) {
  int i = blockIdx.x * blockDim.x + threadIdx.x;
  if (i < n64) {
    float zv = eps[i] * expf(0.5f * lv[i]) + mu[i];
    z[i] = zv;
    zh[i] = __float2half(dinv[i >> 6] * zv);
  }
}

// zg = z @ W_g (commuted: aggregation happens after, in gagg_kernel), stored
// dinv-prescaled fp32. Also emits logits_label = z@W_lc + b_lc.
__global__ __launch_bounds__(256) void zg_kernel(
    const float* __restrict__ z, const float* __restrict__ Wg,
    const float* __restrict__ Wlc, const float* __restrict__ blc,
    const float* __restrict__ dinv, float2* __restrict__ zgs,
    float* __restrict__ out_label, int n) {
  int wid = (blockIdx.x * blockDim.x + threadIdx.x) >> 6;
  int lane = threadIdx.x & 63;
  if (wid >= n) return;
  float zz = z[(size_t)wid * 64 + lane];
  float v0 = zz * Wg[lane * 2 + 0];
  float v1 = zz * Wg[lane * 2 + 1];
  float v2 = zz * Wlc[lane];
  for (int off = 32; off > 0; off >>= 1) {
    v0 += __shfl_xor(v0, off, 64);
    v1 += __shfl_xor(v1, off, 64);
    v2 += __shfl_xor(v2, off, 64);
  }
  if (lane == 0) {
    float di = dinv[wid];
    zgs[wid] = float2{di * v0, di * v1};
    out_label[wid] = v2 + blc[0];
  }
}

// gagg = A_hat * zg (2 feats, fp32-exact path) + gumbel-softmax hard head.
__global__ __launch_bounds__(256) void gagg_kernel(
    const float2* __restrict__ zgs, const int* __restrict__ rowptr,
    const int* __restrict__ csr, const float* __restrict__ dinv,
    const float* __restrict__ bg, const float* __restrict__ u,
    float* __restrict__ out_gender, int n) {
  int wid = (blockIdx.x * blockDim.x + threadIdx.x) >> 6;
  int lane = threadIdx.x & 63;
  if (wid >= n) return;
  int beg = rowptr[wid];
  int end = rowptr[wid + 1];
  float a0 = 0.f, a1 = 0.f;
  for (int k = beg + lane; k < end; k += 64) {
    float2 g = zgs[csr[k]];
    a0 += g.x;
    a1 += g.y;
  }
  for (int off = 32; off > 0; off >>= 1) {
    a0 += __shfl_xor(a0, off, 64);
    a1 += __shfl_xor(a1, off, 64);
  }
  if (lane == 0) {
    float2 self = zgs[wid];
    a0 += self.x;
    a1 += self.y;
    float di = dinv[wid];
    float lg0 = di * a0 + bg[0];
    float lg1 = di * a1 + bg[1];
    float u0 = u[(size_t)wid * 2 + 0];
    float u1 = u[(size_t)wid * 2 + 1];
    float g0 = -logf(-logf(u0 + 1e-20f) + 1e-20f);
    float g1 = -logf(-logf(u1 + 1e-20f) + 1e-20f);
    float aa0 = lg0 + g0, aa1 = lg1 + g1;
    float mx = fmaxf(aa0, aa1);
    float e0 = expf(aa0 - mx), e1 = expf(aa1 - mx);
    float s = e0 + e1;
    float y0 = e0 / s, y1 = e1 / s;
    float h0 = (y1 > y0) ? 0.f : 1.f;  // argmax, first index wins ties
    float h1 = 1.f - h0;
    out_gender[(size_t)wid * 2 + 0] = (h0 - y0) + y0;  // == y_hard forward
    out_gender[(size_t)wid * 2 + 1] = (h1 - y1) + y1;
  }
}

extern "C" void kernel_launch(void* const* d_in, const int* in_sizes, int n_in,
                              void* d_out, int out_size, void* d_ws, size_t ws_size,
                              hipStream_t stream) {
  const float* x   = (const float*)d_in[0];
  const int*   ei  = (const int*)d_in[1];
  const float* eps = (const float*)d_in[2];
  const float* u   = (const float*)d_in[3];
  const float* W1  = (const float*)d_in[4];
  const float* b1  = (const float*)d_in[5];
  const float* Wmu = (const float*)d_in[6];
  const float* bmu = (const float*)d_in[7];
  const float* Wls = (const float*)d_in[8];
  const float* bls = (const float*)d_in[9];
  const float* Wdx = (const float*)d_in[10];
  const float* bdx = (const float*)d_in[11];
  const float* Wg  = (const float*)d_in[12];
  const float* bg  = (const float*)d_in[13];
  const float* Wlc = (const float*)d_in[14];
  const float* blc = (const float*)d_in[15];

  const int n = in_sizes[0] / 128;  // 50000
  const int e = in_sizes[1] / 2;    // 1600000
  const int* esrc = ei;
  const int* edst = ei + e;

  float* out = (float*)d_out;
  float* out_recon  = out;                            // n*128
  float* out_gender = out + (size_t)n * 128;          // n*2
  float* out_label  = out_gender + (size_t)n * 2;     // n
  float* out_mu     = out_label + n;                  // n*64
  float* out_lv     = out_mu + (size_t)n * 64;        // n*64
  float* out_z      = out_lv + (size_t)n * 64;        // n*64

  // Workspace layout (~33 MB). Lifetime-overlapped regions:
  //   Xs (xw staged, dead after spmm1)        <- later zh (z staged)
  //   hb (h staged, dead after spmm2)         <- later zagg (fp32 n*64)
  // hagg fp32 borrows out_recon (free until recon GEMM);
  // binned borrows out_lv (free until logvar GEMM).
  float* dinv  = (float*)d_ws;                    // n
  int* rowptr  = (int*)(dinv + n);                // n+1
  int* part    = rowptr + (n + 1);                // 256
  int* csr     = part + 256;                      // e
  int* gh      = csr + e;                         // NBUCK*NBLK
  __half* Xs   = (__half*)(gh + NBUCK * NBLK);    // n*128 fp16
  __half* hb   = Xs + (size_t)n * 128;            // n*128 fp16
  float* zgs   = (float*)(hb + (size_t)n * 128);  // n*2 fp32
  __half* zh   = Xs;                              // alias (n*64 fp16)
  float* zagg  = (float*)hb;                      // alias (n*64 fp32)
  float* hagg  = out_recon;
  int* binned  = (int*)out_lv;

  const int GH = NBUCK * NBLK;              // 62500
  const int GHB = (GH + 255) / 256;         // 245 (<=256 for scan_p2)
  const int chunk = (e + NBLK - 1) / NBLK;  // 6400

  // --- CSR build: 2-level counting sort ---
  hist_kernel<<<NBLK, 256, 0, stream>>>(edst, gh, e, chunk);
  scan_p1<<<GHB, 256, 0, stream>>>(gh, part, GH);
  scan_p2<<<1, 256, 0, stream>>>(part, GHB, &rowptr[n]);   // total == e
  scan_p3<<<GHB, 256, 0, stream>>>(gh, part, GH);
  scatter_kernel<<<NBLK, 256, 0, stream>>>(esrc, edst, gh, binned, e, chunk);
  final_kernel<<<NBUCK, 256, 0, stream>>>(binned, gh, rowptr, csr, dinv, n, e);

  // --- dense/sparse pipeline ---
  // Xs = fp16(dinv * (x @ W1))
  gemm_kernel<128, 128, 64, 4, false, false, true>
      <<<(n + 31) / 32, 256, 0, stream>>>(x, W1, nullptr, nullptr, Xs, dinv, n);
  // hb = fp16(dinv * relu(A_hat*xw + b1))
  spmm_kernel<128, true, true, true>
      <<<(n + 3) / 4, 256, 0, stream>>>(Xs, hb, rowptr, csr, dinv, b1, n);
  // hagg = A_hat * h  (fp32)
  spmm_kernel<128, false, false, false>
      <<<(n + 3) / 4, 256, 0, stream>>>(hb, hagg, rowptr, csr, dinv, nullptr, n);
  // mu / logvar (fp32; logvar GEMM overwrites binned — dead)
  gemm_kernel<128, 64, 64, 4, true, false, false>
      <<<(n + 63) / 64, 256, 0, stream>>>(hagg, Wmu, bmu, out_mu, nullptr, nullptr, n);
  gemm_kernel<128, 64, 64, 4, true, false, false>
      <<<(n + 63) / 64, 256, 0, stream>>>(hagg, Wls, bls, out_lv, nullptr, nullptr, n);
  // z (fp32 output) + zh staging (overwrites Xs — dead)
  z_kernel<<<(n * 64 + 255) / 256, 256, 0, stream>>>(eps, out_lv, out_mu, out_z, zh, dinv, n * 64);
  // gender logits path (fp32-exact, commuted) + label head
  zg_kernel<<<(n + 3) / 4, 256, 0, stream>>>(out_z, Wg, Wlc, blc, dinv, (float2*)zgs, out_label, n);
  // zagg = A_hat * z (fp16 gather; overwrites hb — dead)
  spmm_kernel<64, false, false, false>
      <<<(n + 3) / 4, 256, 0, stream>>>(zh, zagg, rowptr, csr, dinv, nullptr, n);
  // recon = zagg @ W_dx + b_dx (overwrites hagg — dead)
  gemm_kernel<64, 128, 64, 4, true, false, false>
      <<<(n + 31) / 32, 256, 0, stream>>>(zagg, Wdx, bdx, out_recon, nullptr, nullptr, n);
  // gagg = A_hat * zg -> gumbel-softmax hard head
  gagg_kernel<<<(n + 3) / 4, 256, 0, stream>>>((const float2*)zgs, rowptr, csr, dinv, bg, u, out_gender, n);
}

// Round 6
// 416.562 us; speedup vs baseline: 3.9793x; 1.1704x over previous
//
#include <hip/hip_runtime.h>
#include <hip/hip_fp16.h>
#include <cstddef>

// ---------------------------------------------------------------------------
// GCN-VAE on MI355X.
//   CSR build (2-level LDS counting sort) -> xw=x@W1 (staged fp16*dinv)
//   -> h (spmm128, staged fp16*dinv) -> hagg (spmm128, fp32)
//   -> mlz: mu,logvar,z (+fp8 z staging, +zg gender logits, +label) fused
//   -> spmm_zg: zagg (fp8 gather) + gender aggregation + gumbel head
//   -> recon = zagg@Wdx+b.
// R2: GEMM rewritten (R1 spilled: 850MB spill writes).
// R3: spmm x8 unroll; fill was bound by csr line ping-pong not atomics.
// R4: CSR build as counting sort (scatter into block-private bins).
// R5: fp16 dinv-prescaled staging halves gather bytes; gender conv commuted
//     to (Âz)@Wg-order so the one-hot argmax path stays fp32-exact.
// R6: 256B-align workspace buffers (R5 had Xs/hb at offset%256==20 -> every
//     256B gather row straddled 5 lines, +25% FETCH). Fuse mu/lv/z/zg/label
//     into one mlz kernel (hagg read once, 3 fewer dispatches). z staged fp8
//     (recon-only path; 3.2MB working set -> per-XCD L2-resident) + gagg
//     fused into spmm_zg. fp8 for Xs/hb REJECTED: dz~0.015 -> ~100 gender
//     argmax flips (absmax 1.0 cliff).
// ---------------------------------------------------------------------------

constexpr int R = 200;        // nodes per bucket (n=50000 -> exactly 250 buckets)
constexpr int NBUCK = 250;    // dst buckets
constexpr int NBLK = 250;     // edge-chunk blocks for hist/scatter
constexpr int SLABCAP = 12288;  // csr slab LDS capacity (mean bucket = 6400)

__global__ __launch_bounds__(256) void hist_kernel(
    const int* __restrict__ dst, int* __restrict__ gh, int e, int chunk) {
  __shared__ int h[NBUCK];
  for (int t = threadIdx.x; t < NBUCK; t += 256) h[t] = 0;
  __syncthreads();
  int beg = blockIdx.x * chunk;
  int fin = min(e, beg + chunk);
  for (int i = beg + threadIdx.x; i < fin; i += 256)
    atomicAdd(&h[dst[i] / R], 1);
  __syncthreads();
  for (int t = threadIdx.x; t < NBUCK; t += 256)
    gh[t * NBLK + blockIdx.x] = h[t];
}

__global__ void scan_p1(const int* __restrict__ in, int* __restrict__ part, int n) {
  __shared__ int s[256];
  int i = blockIdx.x * 256 + threadIdx.x;
  s[threadIdx.x] = (i < n) ? in[i] : 0;
  __syncthreads();
  for (int off = 128; off > 0; off >>= 1) {
    if (threadIdx.x < off) s[threadIdx.x] += s[threadIdx.x + off];
    __syncthreads();
  }
  if (threadIdx.x == 0) part[blockIdx.x] = s[0];
}

__global__ void scan_p2(int* __restrict__ part, int nb, int* __restrict__ total_out) {
  __shared__ int s[256];
  int v = (threadIdx.x < nb) ? part[threadIdx.x] : 0;
  s[threadIdx.x] = v;
  __syncthreads();
  for (int off = 1; off < 256; off <<= 1) {
    int t = (threadIdx.x >= off) ? s[threadIdx.x - off] : 0;
    __syncthreads();
    s[threadIdx.x] += t;
    __syncthreads();
  }
  if (threadIdx.x < nb) part[threadIdx.x] = s[threadIdx.x] - v;  // exclusive
  if (threadIdx.x == nb - 1) *total_out = s[threadIdx.x];        // grand total
}

__global__ void scan_p3(int* io, const int* __restrict__ part, int n) {
  __shared__ int s[256];
  int i = blockIdx.x * 256 + threadIdx.x;
  int v = (i < n) ? io[i] : 0;
  s[threadIdx.x] = v;
  __syncthreads();
  for (int off = 1; off < 256; off <<= 1) {
    int t = (threadIdx.x >= off) ? s[threadIdx.x - off] : 0;
    __syncthreads();
    s[threadIdx.x] += t;
    __syncthreads();
  }
  int excl = s[threadIdx.x] - v + part[blockIdx.x];
  if (i < n) io[i] = excl;
}

// Record = (dst%R)<<16 | src  (n<65536). Block-private regions: one
// writeback per 64B line.
__global__ __launch_bounds__(256) void scatter_kernel(
    const int* __restrict__ src, const int* __restrict__ dst,
    const int* __restrict__ ghs, int* __restrict__ binned, int e, int chunk) {
  __shared__ int cur[NBUCK];
  for (int t = threadIdx.x; t < NBUCK; t += 256)
    cur[t] = ghs[t * NBLK + blockIdx.x];
  __syncthreads();
  int beg = blockIdx.x * chunk;
  int fin = min(e, beg + chunk);
  for (int i = beg + threadIdx.x; i < fin; i += 256) {
    int d = dst[i];
    int b = d / R;
    int p = atomicAdd(&cur[b], 1);
    binned[p] = ((d - b * R) << 16) | src[i];
  }
}

__global__ __launch_bounds__(256) void final_kernel(
    const int* __restrict__ binned, const int* __restrict__ ghs,
    int* __restrict__ rowptr, int* __restrict__ csr,
    float* __restrict__ dinv, int n, int e) {
  __shared__ int sdeg[R];
  __shared__ int sscan[256];
  __shared__ int scur[R];
  __shared__ int slab[SLABCAP];
  const int b = blockIdx.x;
  const int tid = threadIdx.x;
  const int base = ghs[b * NBLK];
  const int end = (b < NBUCK - 1) ? ghs[(b + 1) * NBLK] : e;
  const int cnt = end - base;

  if (tid < R) sdeg[tid] = 0;
  __syncthreads();
  for (int k = base + tid; k < end; k += 256)
    atomicAdd(&sdeg[binned[k] >> 16], 1);
  __syncthreads();

  int dv = (tid < R) ? sdeg[tid] : 0;
  sscan[tid] = dv;
  __syncthreads();
  for (int off = 1; off < 256; off <<= 1) {
    int t = (tid >= off) ? sscan[tid - off] : 0;
    __syncthreads();
    sscan[tid] += t;
    __syncthreads();
  }
  int excl = sscan[tid] - dv;
  int node = b * R + tid;
  if (tid < R && node < n) {
    rowptr[node] = base + excl;
    dinv[node] = 1.0f / sqrtf((float)dv + 1.0f);  // +1 self-loop
    scur[tid] = excl;
  }
  __syncthreads();

  const bool fits = (cnt <= SLABCAP);
  for (int k = base + tid; k < end; k += 256) {
    int rec = binned[k];
    int p = atomicAdd(&scur[rec >> 16], 1);
    int s = rec & 0xFFFF;
    if (fits) slab[p] = s;
    else csr[base + p] = s;
  }
  __syncthreads();
  if (fits)
    for (int k = tid; k < cnt; k += 256) csr[base + k] = slab[k];
}

// ---------------------------------------------------------------------------
// GEMM: C[n,M] = A[n,K] @ W[K,M] (+bias)(+relu). HALF_OUT: writes ONLY the
// fp16 dinv-prescaled staging buffer Ch[row] = fp16(dinv[row]*val).
// ---------------------------------------------------------------------------
template <int K, int M, int KT, int RPT, bool BIAS, bool RELU, bool HALF_OUT>
__global__ __launch_bounds__(256, 4) void gemm_kernel(
    const float* __restrict__ A, const float* __restrict__ W,
    const float* __restrict__ bias, float* __restrict__ C,
    __half* __restrict__ Ch, const float* __restrict__ dinv, int n) {
  constexpr int CG = M / 4;
  constexpr int RS = 256 / CG;
  constexpr int RPB = RS * RPT;
  __shared__ float sW[KT * M];
  const int cg = threadIdx.x % CG;
  const int rs = threadIdx.x / CG;
  const int row0 = blockIdx.x * RPB + rs * RPT;

  const float* Arow[RPT];
#pragma unroll
  for (int rr = 0; rr < RPT; ++rr) {
    int row = row0 + rr;
    if (row > n - 1) row = n - 1;
    Arow[rr] = A + (size_t)row * K;
  }

  float4 acc[RPT];
#pragma unroll
  for (int rr = 0; rr < RPT; ++rr) acc[rr] = float4{0.f, 0.f, 0.f, 0.f};

  for (int kt = 0; kt < K; kt += KT) {
    if (kt) __syncthreads();
    for (int i = threadIdx.x * 4; i < KT * M; i += 1024)
      *reinterpret_cast<float4*>(&sW[i]) =
          *reinterpret_cast<const float4*>(&W[kt * M + i]);
    __syncthreads();
#pragma unroll 4
    for (int k4 = 0; k4 < KT; k4 += 4) {
      float4 a[RPT];
#pragma unroll
      for (int rr = 0; rr < RPT; ++rr)
        a[rr] = *reinterpret_cast<const float4*>(Arow[rr] + kt + k4);
#pragma unroll
      for (int j = 0; j < 4; ++j) {
        float4 w = *reinterpret_cast<const float4*>(&sW[(k4 + j) * M + cg * 4]);
#pragma unroll
        for (int rr = 0; rr < RPT; ++rr) {
          float av = reinterpret_cast<const float*>(&a[rr])[j];
          acc[rr].x += av * w.x;
          acc[rr].y += av * w.y;
          acc[rr].z += av * w.z;
          acc[rr].w += av * w.w;
        }
      }
    }
  }

  float4 bv = float4{0.f, 0.f, 0.f, 0.f};
  if (BIAS) bv = *reinterpret_cast<const float4*>(&bias[cg * 4]);
#pragma unroll
  for (int rr = 0; rr < RPT; ++rr) {
    int row = row0 + rr;
    if (row < n) {
      float4 o = acc[rr];
      if (BIAS) { o.x += bv.x; o.y += bv.y; o.z += bv.z; o.w += bv.w; }
      if (RELU) {
        o.x = fmaxf(o.x, 0.f); o.y = fmaxf(o.y, 0.f);
        o.z = fmaxf(o.z, 0.f); o.w = fmaxf(o.w, 0.f);
      }
      if (HALF_OUT) {
        float di = dinv[row];
        __half2* dst = reinterpret_cast<__half2*>(Ch + (size_t)row * M + cg * 4);
        dst[0] = __floats2half2_rn(di * o.x, di * o.y);
        dst[1] = __floats2half2_rn(di * o.z, di * o.w);
      } else {
        *reinterpret_cast<float4*>(&C[(size_t)row * M + cg * 4]) = o;
      }
    }
  }
}

// ---------------------------------------------------------------------------
// SpMM (F=128) on fp16 dinv-prescaled input Xs (Xs[i] = dinv[i]*X[i]):
//   Y[i] = dinv[i] * (sum_{dst=i} Xs[src] + Xs[i]) (+bias)(+relu)
// One wave per node; x8-unrolled gather. HALF_OUT: fp16 dinv-prescaled out.
// ---------------------------------------------------------------------------
template <bool BIAS, bool RELU, bool HALF_OUT>
__global__ __launch_bounds__(256) void spmm128_kernel(
    const __half* __restrict__ Xs, void* __restrict__ Yout,
    const int* __restrict__ rowptr, const int* __restrict__ csr,
    const float* __restrict__ dinv, const float* __restrict__ bias, int n) {
  int wid = (blockIdx.x * blockDim.x + threadIdx.x) >> 6;
  int lane = threadIdx.x & 63;
  if (wid >= n) return;
  int beg = rowptr[wid];
  int end = rowptr[wid + 1];
  constexpr int U = 8;
  float a0[U], a1[U];
#pragma unroll
  for (int uu = 0; uu < U; ++uu) { a0[uu] = 0.f; a1[uu] = 0.f; }

  for (int base = beg; base < end; base += 64) {
    int m = end - base;
    if (m > 64) m = 64;
    int idx = (lane < m) ? csr[base + lane] : 0;
    int j = 0;
    for (; j + U <= m; j += U) {
      const __half2* rows[U];
#pragma unroll
      for (int uu = 0; uu < U; ++uu)
        rows[uu] = reinterpret_cast<const __half2*>(
            Xs + (size_t)__shfl(idx, j + uu, 64) * 128);
      __half2 v[U];
#pragma unroll
      for (int uu = 0; uu < U; ++uu) v[uu] = rows[uu][lane];
#pragma unroll
      for (int uu = 0; uu < U; ++uu) {
        float2 f = __half22float2(v[uu]);
        a0[uu] += f.x;
        a1[uu] += f.y;
      }
    }
    for (; j < m; ++j) {
      const __half2* row = reinterpret_cast<const __half2*>(
          Xs + (size_t)__shfl(idx, j, 64) * 128);
      float2 f = __half22float2(row[lane]);
      a0[0] += f.x;
      a1[0] += f.y;
    }
  }

  float t0 = 0.f, t1 = 0.f;
#pragma unroll
  for (int uu = 0; uu < U; ++uu) { t0 += a0[uu]; t1 += a1[uu]; }

  // self-loop: + Xs[wid]
  float2 sf = __half22float2(
      reinterpret_cast<const __half2*>(Xs + (size_t)wid * 128)[lane]);
  t0 += sf.x;
  t1 += sf.y;

  float di = dinv[wid];
  float r0 = di * t0;
  float r1 = di * t1;
  if (BIAS) { r0 += bias[lane * 2]; r1 += bias[lane * 2 + 1]; }
  if (RELU) { r0 = fmaxf(r0, 0.f); r1 = fmaxf(r1, 0.f); }

  if (HALF_OUT) {
    reinterpret_cast<__half2*>((__half*)Yout + (size_t)wid * 128)[lane] =
        __floats2half2_rn(di * r0, di * r1);
  } else {
    float2 o = {r0, r1};
    reinterpret_cast<float2*>((float*)Yout + (size_t)wid * 128)[lane] = o;
  }
}

// ---------------------------------------------------------------------------
// mlz: fused mu/logvar GEMMs (hagg read ONCE) + z + fp8 z-staging + gender
// logits (commuted, fp32-exact) + label head.
//   mu = hagg@Wmu+bmu ; lv = hagg@Wls+bls ; z = eps*exp(0.5lv)+mu
//   zh8 = fp8(dinv*z) ; zgs = dinv*(z@Wg) ; label = z@Wlc+blc
// Block: 16 col-groups x 16 row-slots x RPT=4 rows. Both W tiles in LDS.
// ---------------------------------------------------------------------------
__global__ __launch_bounds__(256, 4) void mlz_kernel(
    const float* __restrict__ hagg,
    const float* __restrict__ Wmu, const float* __restrict__ bmu,
    const float* __restrict__ Wls, const float* __restrict__ bls,
    const float* __restrict__ eps, const float* __restrict__ dinv,
    const float* __restrict__ Wg, const float* __restrict__ Wlc,
    const float* __restrict__ blc,
    float* __restrict__ out_mu, float* __restrict__ out_lv,
    float* __restrict__ out_z, unsigned int* __restrict__ zh8,
    float2* __restrict__ zgs, float* __restrict__ out_label, int n) {
  constexpr int K = 128, M = 64, KT = 64, RPT = 4;
  constexpr int CG = M / 4;       // 16
  constexpr int RS = 256 / CG;    // 16
  constexpr int RPB = RS * RPT;   // 64
  __shared__ float sWm[KT * M];
  __shared__ float sWl[KT * M];
  const int cg = threadIdx.x % CG;
  const int rs = threadIdx.x / CG;
  const int row0 = blockIdx.x * RPB + rs * RPT;

  const float* Arow[RPT];
#pragma unroll
  for (int rr = 0; rr < RPT; ++rr) {
    int row = row0 + rr;
    if (row > n - 1) row = n - 1;
    Arow[rr] = hagg + (size_t)row * K;
  }

  float4 am[RPT], al[RPT];
#pragma unroll
  for (int rr = 0; rr < RPT; ++rr) {
    am[rr] = float4{0.f, 0.f, 0.f, 0.f};
    al[rr] = float4{0.f, 0.f, 0.f, 0.f};
  }

  for (int kt = 0; kt < K; kt += KT) {
    if (kt) __syncthreads();
    for (int i = threadIdx.x * 4; i < KT * M; i += 1024) {
      *reinterpret_cast<float4*>(&sWm[i]) =
          *reinterpret_cast<const float4*>(&Wmu[kt * M + i]);
      *reinterpret_cast<float4*>(&sWl[i]) =
          *reinterpret_cast<const float4*>(&Wls[kt * M + i]);
    }
    __syncthreads();
#pragma unroll 2
    for (int k4 = 0; k4 < KT; k4 += 4) {
      float4 a[RPT];
#pragma unroll
      for (int rr = 0; rr < RPT; ++rr)
        a[rr] = *reinterpret_cast<const float4*>(Arow[rr] + kt + k4);
#pragma unroll
      for (int j = 0; j < 4; ++j) {
        float4 wm = *reinterpret_cast<const float4*>(&sWm[(k4 + j) * M + cg * 4]);
        float4 wl = *reinterpret_cast<const float4*>(&sWl[(k4 + j) * M + cg * 4]);
#pragma unroll
        for (int rr = 0; rr < RPT; ++rr) {
          float av = reinterpret_cast<const float*>(&a[rr])[j];
          am[rr].x += av * wm.x; am[rr].y += av * wm.y;
          am[rr].z += av * wm.z; am[rr].w += av * wm.w;
          al[rr].x += av * wl.x; al[rr].y += av * wl.y;
          al[rr].z += av * wl.z; al[rr].w += av * wl.w;
        }
      }
    }
  }

  float4 bm = *reinterpret_cast<const float4*>(&bmu[cg * 4]);
  float4 bl = *reinterpret_cast<const float4*>(&bls[cg * 4]);
  float wg0[4], wg1[4], wlcv[4];
#pragma unroll
  for (int cc = 0; cc < 4; ++cc) {
    int c = cg * 4 + cc;
    wg0[cc] = Wg[c * 2 + 0];
    wg1[cc] = Wg[c * 2 + 1];
    wlcv[cc] = Wlc[c];
  }
  float blc0 = blc[0];

#pragma unroll
  for (int rr = 0; rr < RPT; ++rr) {
    int row = row0 + rr;
    if (row < n) {  // uniform across the 16-lane cg-group
      float4 mu4 = {am[rr].x + bm.x, am[rr].y + bm.y,
                    am[rr].z + bm.z, am[rr].w + bm.w};
      float4 lv4 = {al[rr].x + bl.x, al[rr].y + bl.y,
                    al[rr].z + bl.z, al[rr].w + bl.w};
      float4 e4 = *reinterpret_cast<const float4*>(&eps[(size_t)row * 64 + cg * 4]);
      float4 z4 = {e4.x * expf(0.5f * lv4.x) + mu4.x,
                   e4.y * expf(0.5f * lv4.y) + mu4.y,
                   e4.z * expf(0.5f * lv4.z) + mu4.z,
                   e4.w * expf(0.5f * lv4.w) + mu4.w};
      *reinterpret_cast<float4*>(&out_mu[(size_t)row * 64 + cg * 4]) = mu4;
      *reinterpret_cast<float4*>(&out_lv[(size_t)row * 64 + cg * 4]) = lv4;
      *reinterpret_cast<float4*>(&out_z[(size_t)row * 64 + cg * 4]) = z4;
      float di = dinv[row];
      int pw = __builtin_amdgcn_cvt_pk_fp8_f32(di * z4.x, di * z4.y, 0, false);
      pw = __builtin_amdgcn_cvt_pk_fp8_f32(di * z4.z, di * z4.w, pw, true);
      zh8[(size_t)row * 16 + cg] = (unsigned int)pw;
      float pg0 = z4.x * wg0[0] + z4.y * wg0[1] + z4.z * wg0[2] + z4.w * wg0[3];
      float pg1 = z4.x * wg1[0] + z4.y * wg1[1] + z4.z * wg1[2] + z4.w * wg1[3];
      float pl  = z4.x * wlcv[0] + z4.y * wlcv[1] + z4.z * wlcv[2] + z4.w * wlcv[3];
#pragma unroll
      for (int off = 1; off < 16; off <<= 1) {
        pg0 += __shfl_xor(pg0, off, 64);
        pg1 += __shfl_xor(pg1, off, 64);
        pl  += __shfl_xor(pl, off, 64);
      }
      if (cg == 0) {
        zgs[row] = float2{di * pg0, di * pg1};
        out_label[row] = pl + blc0;
      }
    }
  }
}

// ---------------------------------------------------------------------------
// spmm_zg: zagg = A_hat*z via fp8 gather (3.2MB working set: per-XCD
// L2-resident) + fused gender aggregation (fp32 zgs gather rides the same
// csr walk) + gumbel-softmax hard head.
// ---------------------------------------------------------------------------
__global__ __launch_bounds__(256) void spmm_zg_kernel(
    const unsigned char* __restrict__ zh8, const float2* __restrict__ zgs,
    float* __restrict__ zagg, const int* __restrict__ rowptr,
    const int* __restrict__ csr, const float* __restrict__ dinv,
    const float* __restrict__ bg, const float* __restrict__ u,
    float* __restrict__ out_gender, int n) {
  int wid = (blockIdx.x * blockDim.x + threadIdx.x) >> 6;
  int lane = threadIdx.x & 63;
  if (wid >= n) return;
  int beg = rowptr[wid];
  int end = rowptr[wid + 1];
  constexpr int U = 8;
  float acc[U];
#pragma unroll
  for (int uu = 0; uu < U; ++uu) acc[uu] = 0.f;
  float ga0 = 0.f, ga1 = 0.f;

  for (int base = beg; base < end; base += 64) {
    int m = end - base;
    if (m > 64) m = 64;
    int idx = 0;
    if (lane < m) {
      idx = csr[base + lane];
      float2 g = zgs[idx];   // per-lane gender-logit accumulation
      ga0 += g.x;
      ga1 += g.y;
    }
    int j = 0;
    for (; j + U <= m; j += U) {
      const unsigned char* rows[U];
#pragma unroll
      for (int uu = 0; uu < U; ++uu)
        rows[uu] = zh8 + (size_t)__shfl(idx, j + uu, 64) * 64;
      int b[U];
#pragma unroll
      for (int uu = 0; uu < U; ++uu) b[uu] = (int)rows[uu][lane];
#pragma unroll
      for (int uu = 0; uu < U; ++uu)
        acc[uu] += __builtin_amdgcn_cvt_f32_fp8(b[uu], 0);
    }
    for (; j < m; ++j) {
      const unsigned char* row = zh8 + (size_t)__shfl(idx, j, 64) * 64;
      acc[0] += __builtin_amdgcn_cvt_f32_fp8((int)row[lane], 0);
    }
  }

  float t = 0.f;
#pragma unroll
  for (int uu = 0; uu < U; ++uu) t += acc[uu];
  t += __builtin_amdgcn_cvt_f32_fp8((int)zh8[(size_t)wid * 64 + lane], 0);

  float di = dinv[wid];
  zagg[(size_t)wid * 64 + lane] = di * t;

  for (int off = 32; off > 0; off >>= 1) {
    ga0 += __shfl_xor(ga0, off, 64);
    ga1 += __shfl_xor(ga1, off, 64);
  }
  if (lane == 0) {
    float2 self = zgs[wid];
    ga0 += self.x;
    ga1 += self.y;
    float lg0 = di * ga0 + bg[0];
    float lg1 = di * ga1 + bg[1];
    float u0 = u[(size_t)wid * 2 + 0];
    float u1 = u[(size_t)wid * 2 + 1];
    float g0 = -logf(-logf(u0 + 1e-20f) + 1e-20f);
    float g1 = -logf(-logf(u1 + 1e-20f) + 1e-20f);
    float a0 = lg0 + g0, a1 = lg1 + g1;
    float mx = fmaxf(a0, a1);
    float e0 = expf(a0 - mx), e1 = expf(a1 - mx);
    float s = e0 + e1;
    float y0 = e0 / s, y1 = e1 / s;
    float h0 = (y1 > y0) ? 0.f : 1.f;  // argmax, first index wins ties
    float h1 = 1.f - h0;
    out_gender[(size_t)wid * 2 + 0] = (h0 - y0) + y0;
    out_gender[(size_t)wid * 2 + 1] = (h1 - y1) + y1;
  }
}

extern "C" void kernel_launch(void* const* d_in, const int* in_sizes, int n_in,
                              void* d_out, int out_size, void* d_ws, size_t ws_size,
                              hipStream_t stream) {
  const float* x   = (const float*)d_in[0];
  const int*   ei  = (const int*)d_in[1];
  const float* eps = (const float*)d_in[2];
  const float* u   = (const float*)d_in[3];
  const float* W1  = (const float*)d_in[4];
  const float* b1  = (const float*)d_in[5];
  const float* Wmu = (const float*)d_in[6];
  const float* bmu = (const float*)d_in[7];
  const float* Wls = (const float*)d_in[8];
  const float* bls = (const float*)d_in[9];
  const float* Wdx = (const float*)d_in[10];
  const float* bdx = (const float*)d_in[11];
  const float* Wg  = (const float*)d_in[12];
  const float* bg  = (const float*)d_in[13];
  const float* Wlc = (const float*)d_in[14];
  const float* blc = (const float*)d_in[15];

  const int n = in_sizes[0] / 128;  // 50000
  const int e = in_sizes[1] / 2;    // 1600000
  const int* esrc = ei;
  const int* edst = ei + e;

  float* out = (float*)d_out;
  float* out_recon  = out;                            // n*128
  float* out_gender = out + (size_t)n * 128;          // n*2
  float* out_label  = out_gender + (size_t)n * 2;     // n
  float* out_mu     = out_label + n;                  // n*64
  float* out_lv     = out_mu + (size_t)n * 64;        // n*64
  float* out_z      = out_lv + (size_t)n * 64;        // n*64

  // Workspace layout, every buffer 256B-aligned (R5 had Xs at offset%256==20:
  // every gathered 256B row straddled an extra cache line).
  char* w = (char*)d_ws;
  size_t off = 0;
  auto alloc = [&](size_t bytes) {
    char* p = w + off;
    off = (off + bytes + 255) & ~(size_t)255;
    return p;
  };
  float* dinv  = (float*)alloc((size_t)n * 4);
  int* rowptr  = (int*)alloc((size_t)(n + 1) * 4);
  int* part    = (int*)alloc(256 * 4);
  int* csr     = (int*)alloc((size_t)e * 4);
  int* gh      = (int*)alloc((size_t)NBUCK * NBLK * 4);
  __half* Xs   = (__half*)alloc((size_t)n * 128 * 2);  // later: zh8 (n*64 B)
  __half* hb   = (__half*)alloc((size_t)n * 128 * 2);  // later: zagg (n*64 f32)
  float2* zgs  = (float2*)alloc((size_t)n * 8);
  unsigned char* zh8 = (unsigned char*)Xs;  // alias (Xs dead after spmm1)
  float* zagg  = (float*)hb;                // alias (hb dead after spmm2)
  float* hagg  = out_recon;                 // free until recon GEMM
  int* binned  = (int*)out_lv;              // free until mlz writes out_lv

  const int GH = NBUCK * NBLK;              // 62500
  const int GHB = (GH + 255) / 256;         // 245 (<=256 for scan_p2)
  const int chunk = (e + NBLK - 1) / NBLK;  // 6400

  // --- CSR build: 2-level counting sort ---
  hist_kernel<<<NBLK, 256, 0, stream>>>(edst, gh, e, chunk);
  scan_p1<<<GHB, 256, 0, stream>>>(gh, part, GH);
  scan_p2<<<1, 256, 0, stream>>>(part, GHB, &rowptr[n]);   // total == e
  scan_p3<<<GHB, 256, 0, stream>>>(gh, part, GH);
  scatter_kernel<<<NBLK, 256, 0, stream>>>(esrc, edst, gh, binned, e, chunk);
  final_kernel<<<NBUCK, 256, 0, stream>>>(binned, gh, rowptr, csr, dinv, n, e);

  // --- dense/sparse pipeline ---
  // Xs = fp16(dinv * (x @ W1))
  gemm_kernel<128, 128, 64, 4, false, false, true>
      <<<(n + 31) / 32, 256, 0, stream>>>(x, W1, nullptr, nullptr, Xs, dinv, n);
  // hb = fp16(dinv * relu(A_hat*xw + b1))
  spmm128_kernel<true, true, true>
      <<<(n + 3) / 4, 256, 0, stream>>>(Xs, hb, rowptr, csr, dinv, b1, n);
  // hagg = A_hat * h  (fp32, into out_recon region)
  spmm128_kernel<false, false, false>
      <<<(n + 3) / 4, 256, 0, stream>>>(hb, hagg, rowptr, csr, dinv, nullptr, n);
  // mu / lv / z / zh8 / zgs / label — fused (overwrites binned via out_lv: dead)
  mlz_kernel<<<(n + 63) / 64, 256, 0, stream>>>(
      hagg, Wmu, bmu, Wls, bls, eps, dinv, Wg, Wlc, blc,
      out_mu, out_lv, out_z, (unsigned int*)zh8, zgs, out_label, n);
  // zagg (fp8 gather) + gender aggregation + gumbel head
  spmm_zg_kernel<<<(n + 3) / 4, 256, 0, stream>>>(
      zh8, (const float2*)zgs, zagg, rowptr, csr, dinv, bg, u, out_gender, n);
  // recon = zagg @ W_dx + b_dx (overwrites hagg — dead)
  gemm_kernel<64, 128, 64, 4, true, false, false>
      <<<(n + 31) / 32, 256, 0, stream>>>(zagg, Wdx, bdx, out_recon, nullptr, nullptr, n);
}